// Round 2
// baseline (5629.642 us; speedup 1.0000x reference)
//
#include <hip/hip_runtime.h>
#include <hip/hip_bf16.h>
#include <math.h>

#define N_NODES 32768
#define N_EDGES 262144
#define N_GRAPHS 512
#define IN_DIM 300
#define HID 128
#define HEADS 4
#define D_FUSED 512
#define N_LAYERS 3

typedef __hip_bfloat16 bf16;

__device__ __forceinline__ float to_f(float v) { return v; }
__device__ __forceinline__ float to_f(bf16 v) { return __bfloat162float(v); }

template <typename T> __device__ __forceinline__ T from_f(float v);
template <> __device__ __forceinline__ float from_f<float>(float v) { return v; }
template <> __device__ __forceinline__ bf16 from_f<bf16>(float v) { return __float2bfloat16(v); }

__device__ __forceinline__ float2 ldbf2(const bf16* p)
{
    const __hip_bfloat162 v = *(const __hip_bfloat162*)p;
    return make_float2(__bfloat162float(v.x), __bfloat162float(v.y));
}

// ---------------------------------------------------------------------------
// Tiled GEMM, fp32 accumulate: C[M,Ncols] = act(A[M,K] @ W[K,Ncols] + bias)
// A: TA (fp32 or bf16), W/bias: fp32, C: TC. BM=BN=64, BK=16, 256 thr, 4x4/thr.
// Grid covers M,Ncols exactly (M%64==0, Ncols%64==0); K guarded.
// ---------------------------------------------------------------------------
template <typename TA, typename TC, int ACT>
__global__ __launch_bounds__(256) void gemm_bias_kernel(
    const TA* __restrict__ A, int lda,
    const float* __restrict__ W, int ldw,
    const float* __restrict__ bias,
    TC* __restrict__ C, int ldc, int K)
{
    __shared__ float As[64][17];
    __shared__ float Ws[16][65];

    const int t = threadIdx.x;
    const int tx = t & 15, ty = t >> 4;
    const int brow = blockIdx.x * 64;
    const int bcol = blockIdx.y * 64;

    float acc[4][4] = {};

    for (int k0 = 0; k0 < K; k0 += 16) {
#pragma unroll
        for (int i = 0; i < 4; ++i) {
            int e = t + 256 * i;
            int r = e >> 4, kk = e & 15;
            int gk = k0 + kk;
            As[r][kk] = (gk < K) ? to_f(A[(size_t)(brow + r) * lda + gk]) : 0.f;
        }
#pragma unroll
        for (int i = 0; i < 4; ++i) {
            int e = t + 256 * i;
            int kk = e >> 6, c = e & 63;
            int gk = k0 + kk;
            Ws[kk][c] = (gk < K) ? W[(size_t)gk * ldw + bcol + c] : 0.f;
        }
        __syncthreads();
#pragma unroll
        for (int kk = 0; kk < 16; ++kk) {
            float a[4], b[4];
#pragma unroll
            for (int i = 0; i < 4; ++i) a[i] = As[ty * 4 + i][kk];
#pragma unroll
            for (int j = 0; j < 4; ++j) b[j] = Ws[kk][tx * 4 + j];
#pragma unroll
            for (int i = 0; i < 4; ++i)
#pragma unroll
                for (int j = 0; j < 4; ++j) acc[i][j] += a[i] * b[j];
        }
        __syncthreads();
    }

#pragma unroll
    for (int i = 0; i < 4; ++i) {
        const size_t r = brow + ty * 4 + i;
#pragma unroll
        for (int j = 0; j < 4; ++j) {
            const int c = bcol + tx * 4 + j;
            float vout = acc[i][j] + bias[c];
            if (ACT == 1) vout = fmaxf(vout, 0.f);
            C[r * ldc + c] = from_f<TC>(vout);
        }
    }
}

// ---------------------------------------------------------------------------
// CSR build
// ---------------------------------------------------------------------------
__global__ void zero_int_kernel(int* __restrict__ p, int n)
{
    int i = blockIdx.x * 256 + threadIdx.x;
    if (i < n) p[i] = 0;
}

__global__ void hist_kernel(const int* __restrict__ dst, int* __restrict__ deg, int E)
{
    int e = blockIdx.x * 256 + threadIdx.x;
    if (e < E) atomicAdd(&deg[dst[e]], 1);
}

__global__ __launch_bounds__(1024) void scan_kernel(const int* __restrict__ deg,
                                                    int* __restrict__ off, int n)
{
    __shared__ int sums[1024];
    int t = threadIdx.x;
    int per = (n + 1023) / 1024;
    int start = t * per;
    int s = 0;
    for (int i = 0; i < per && start + i < n; ++i) s += deg[start + i];
    sums[t] = s;
    __syncthreads();
    for (int ofs = 1; ofs < 1024; ofs <<= 1) {
        int vPrev = (t >= ofs) ? sums[t - ofs] : 0;
        __syncthreads();
        sums[t] += vPrev;
        __syncthreads();
    }
    int run = (t == 0) ? 0 : sums[t - 1];
    for (int i = 0; i < per && start + i < n; ++i) {
        off[start + i] = run;
        run += deg[start + i];
    }
    if (t == 1023) off[n] = run;
}

__global__ void scatter_kernel(const int* __restrict__ src, const int* __restrict__ dst,
                               const int* __restrict__ off, int* __restrict__ cursor,
                               int* __restrict__ csr_src, int E)
{
    int e = blockIdx.x * 256 + threadIdx.x;
    if (e < E) {
        int d = dst[e];
        int pos = atomicAdd(&cursor[d], 1);
        csr_src[off[d] + pos] = src[e];
    }
}

// ---------------------------------------------------------------------------
// Per-head online-softmax attention. One wave per node; lane holds 2 of the
// 128 head dims. hsl points at h_new column slice (row stride D_FUSED) which
// already contains the skip projection; we add the attention output and relu.
// ---------------------------------------------------------------------------
__global__ __launch_bounds__(64) void attn_head_kernel(
    const bf16* __restrict__ q, const bf16* __restrict__ k, const bf16* __restrict__ v,
    bf16* __restrict__ hsl, const int* __restrict__ off, const int* __restrict__ csr)
{
    const int n = blockIdx.x;
    const int lane = threadIdx.x;
    const float scale = 0.08838834764831845f;  // 1/sqrt(128)

    const float2 qv = ldbf2(q + (size_t)n * HID + lane * 2);

    float m = -INFINITY, z = 0.f;
    float2 acc = make_float2(0.f, 0.f);

    const int s0 = off[n], s1 = off[n + 1];
    for (int e = s0; e < s1; ++e) {
        const int s = csr[e];
        const float2 kv = ldbf2(k + (size_t)s * HID + lane * 2);
        float part = qv.x * kv.x + qv.y * kv.y;
#pragma unroll
        for (int o = 32; o; o >>= 1) part += __shfl_xor(part, o);
        const float logit = part * scale;
        const float mn = fmaxf(m, logit);
        const float corr = __expf(m - mn);   // 0 on first edge (m = -inf)
        const float wgt = __expf(logit - mn);
        z = z * corr + wgt;
        const float2 vv = ldbf2(v + (size_t)s * HID + lane * 2);
        acc.x = acc.x * corr + wgt * vv.x;
        acc.y = acc.y * corr + wgt * vv.y;
        m = mn;
    }

    const float inv = 1.f / (z + 1e-16f);
    const size_t ob = (size_t)n * D_FUSED + lane * 2;
    const float2 sk = ldbf2(hsl + ob);
    __hip_bfloat162 o2;
    o2.x = __float2bfloat16(fmaxf(acc.x * inv + sk.x, 0.f));
    o2.y = __float2bfloat16(fmaxf(acc.y * inv + sk.y, 0.f));
    *(__hip_bfloat162*)(hsl + ob) = o2;
}

// ---------------------------------------------------------------------------
// Mean-pool per graph (batch sorted -> binary-search the node range).
// ---------------------------------------------------------------------------
__global__ __launch_bounds__(256) void pool_kernel(const bf16* __restrict__ h,
                                                   const int* __restrict__ batch,
                                                   float* __restrict__ pooled)
{
    const int g = blockIdx.x;
    int a = 0, b = N_NODES;
    while (a < b) { int mid = (a + b) >> 1; if (batch[mid] < g) a = mid + 1; else b = mid; }
    const int start = a;
    b = N_NODES;
    while (a < b) { int mid = (a + b) >> 1; if (batch[mid] < g + 1) a = mid + 1; else b = mid; }
    const int end = a;
    const float invc = 1.f / fmaxf((float)(end - start), 1.f);

    const int t = threadIdx.x;
    float2 s = make_float2(0.f, 0.f);
    for (int nidx = start; nidx < end; ++nidx) {
        const float2 hv = ldbf2(h + (size_t)nidx * D_FUSED + t * 2);
        s.x += hv.x; s.y += hv.y;
    }
    pooled[(size_t)g * D_FUSED + t * 2]     = s.x * invc;
    pooled[(size_t)g * D_FUSED + t * 2 + 1] = s.y * invc;
}

// ---------------------------------------------------------------------------
// Classifier: hid = relu(pooled @ w1 + b1); out = sigmoid(hid @ w2 + b2)
// ---------------------------------------------------------------------------
__global__ __launch_bounds__(128) void cls_kernel(const float* __restrict__ pooled,
                                                  const float* __restrict__ w1,
                                                  const float* __restrict__ b1,
                                                  const float* __restrict__ w2,
                                                  const float* __restrict__ b2,
                                                  float* __restrict__ out)
{
    const int g = blockIdx.x;
    const int j = threadIdx.x;  // 0..127
    const float* p = pooled + (size_t)g * D_FUSED;
    float acc = 0.f;
    for (int i = 0; i < D_FUSED; ++i) acc += p[i] * w1[i * HID + j];
    const float hid = fmaxf(acc + b1[j], 0.f);
    float val = hid * w2[j];
#pragma unroll
    for (int o = 32; o; o >>= 1) val += __shfl_xor(val, o);
    __shared__ float ws2[2];
    if ((threadIdx.x & 63) == 0) ws2[threadIdx.x >> 6] = val;
    __syncthreads();
    if (threadIdx.x == 0) {
        const float sum = ws2[0] + ws2[1] + b2[0];
        out[g] = 1.f / (1.f + __expf(-sum));
    }
}

// ---------------------------------------------------------------------------
extern "C" void kernel_launch(void* const* d_in, const int* in_sizes, int n_in,
                              void* d_out, int out_size, void* d_ws, size_t ws_size,
                              hipStream_t stream)
{
    const float* x        = (const float*)d_in[0];
    const int*   ei       = (const int*)d_in[1];
    const int*   batch    = (const int*)d_in[2];
    const float* syn_w    = (const float*)d_in[3];
    const float* syn_b    = (const float*)d_in[4];
    const float* ant_w    = (const float*)d_in[5];
    const float* ant_b    = (const float*)d_in[6];
    const float* fusion_w = (const float*)d_in[7];
    const float* fusion_b = (const float*)d_in[8];
    const float* Wq       = (const float*)d_in[9];
    const float* bq       = (const float*)d_in[10];
    const float* Wk       = (const float*)d_in[11];
    const float* bk       = (const float*)d_in[12];
    const float* Wv       = (const float*)d_in[13];
    const float* bv       = (const float*)d_in[14];
    const float* Wskip    = (const float*)d_in[15];
    const float* bskip    = (const float*)d_in[16];
    const float* cls_w1   = (const float*)d_in[17];
    const float* cls_b1   = (const float*)d_in[18];
    const float* cls_w2   = (const float*)d_in[19];
    const float* cls_b2   = (const float*)d_in[20];

    const int* src = ei;
    const int* dst = ei + N_EDGES;

    // ---- workspace layout (~95 MB) ----
    bf16* hA = (bf16*)d_ws;                           // N*512 bf16 (32 MB)
    bf16* hB = hA + (size_t)N_NODES * D_FUSED;        // N*512 bf16 (32 MB)
    bf16* qh = hB + (size_t)N_NODES * D_FUSED;        // N*128 bf16 (8 MB)
    bf16* kh = qh + (size_t)N_NODES * HID;            // N*128 bf16 (8 MB)
    bf16* vh = kh + (size_t)N_NODES * HID;            // N*128 bf16 (8 MB)
    float* pooled = (float*)(vh + (size_t)N_NODES * HID);  // G*512 f32 (1 MB)
    int* deg    = (int*)(pooled + (size_t)N_GRAPHS * D_FUSED);  // N
    int* cursor = deg + N_NODES;                                 // N
    int* off    = cursor + N_NODES;                              // N+1
    int* csr    = off + N_NODES + 1;                             // E

    bf16* tenc = qh;  // encoder temp, N*256 bf16 (spans qh..kh)

    // ---- CSR build (zero-fill via kernel; deg & cursor are adjacent) ----
    zero_int_kernel<<<(2 * N_NODES + 255) / 256, 256, 0, stream>>>(deg, 2 * N_NODES);
    hist_kernel<<<(N_EDGES + 255) / 256, 256, 0, stream>>>(dst, deg, N_EDGES);
    scan_kernel<<<1, 1024, 0, stream>>>(deg, off, N_NODES);
    scatter_kernel<<<(N_EDGES + 255) / 256, 256, 0, stream>>>(src, dst, off, cursor, csr, N_EDGES);

    // ---- Encoder ----
    gemm_bias_kernel<float, bf16, 1><<<dim3(N_NODES / 64, 2), 256, 0, stream>>>(
        x, IN_DIM, syn_w, HID, syn_b, tenc, 2 * HID, IN_DIM);
    gemm_bias_kernel<float, bf16, 1><<<dim3(N_NODES / 64, 2), 256, 0, stream>>>(
        x, IN_DIM, ant_w, HID, ant_b, tenc + HID, 2 * HID, IN_DIM);
    gemm_bias_kernel<bf16, bf16, 0><<<dim3(N_NODES / 64, 8), 256, 0, stream>>>(
        tenc, 2 * HID, fusion_w, D_FUSED, fusion_b, hA, D_FUSED, 2 * HID);

    // ---- Transformer layers ----
    bf16* hcur = hA;
    bf16* hnew = hB;
    for (int l = 0; l < N_LAYERS; ++l) {
        const size_t wo = (size_t)l * D_FUSED * D_FUSED;
        const size_t bo = (size_t)l * D_FUSED;
        // skip projection -> hnew (full 512 cols)
        gemm_bias_kernel<bf16, bf16, 0><<<dim3(N_NODES / 64, 8), 256, 0, stream>>>(
            hcur, D_FUSED, Wskip + wo, D_FUSED, bskip + bo, hnew, D_FUSED, D_FUSED);
        for (int hd = 0; hd < HEADS; ++hd) {
            const int co = hd * HID;  // column offset into the 512-wide projections
            gemm_bias_kernel<bf16, bf16, 0><<<dim3(N_NODES / 64, 2), 256, 0, stream>>>(
                hcur, D_FUSED, Wq + wo + co, D_FUSED, bq + bo + co, qh, HID, D_FUSED);
            gemm_bias_kernel<bf16, bf16, 0><<<dim3(N_NODES / 64, 2), 256, 0, stream>>>(
                hcur, D_FUSED, Wk + wo + co, D_FUSED, bk + bo + co, kh, HID, D_FUSED);
            gemm_bias_kernel<bf16, bf16, 0><<<dim3(N_NODES / 64, 2), 256, 0, stream>>>(
                hcur, D_FUSED, Wv + wo + co, D_FUSED, bv + bo + co, vh, HID, D_FUSED);
            attn_head_kernel<<<N_NODES, 64, 0, stream>>>(qh, kh, vh, hnew + co, off, csr);
        }
        bf16* tmp = hcur; hcur = hnew; hnew = tmp;
    }

    // ---- Pool + classify ----
    pool_kernel<<<N_GRAPHS, 256, 0, stream>>>(hcur, batch, pooled);
    cls_kernel<<<N_GRAPHS, 128, 0, stream>>>(pooled, cls_w1, cls_b1, cls_w2, cls_b2,
                                             (float*)d_out);
}

// Round 3
// 982.224 us; speedup vs baseline: 5.7315x; 5.7315x over previous
//
#include <hip/hip_runtime.h>
#include <hip/hip_bf16.h>
#include <math.h>

#define N_NODES 32768
#define N_EDGES 262144
#define N_GRAPHS 512
#define IN_DIM 300
#define KPAD 320
#define HID 128
#define HEADS 4
#define D_FUSED 512
#define N_LAYERS 3

typedef __hip_bfloat16 bf16;
typedef short bf16x8 __attribute__((ext_vector_type(8)));
typedef float f32x4 __attribute__((ext_vector_type(4)));

__device__ __forceinline__ float2 ldbf2(const bf16* p)
{
    const __hip_bfloat162 v = *(const __hip_bfloat162*)p;
    return make_float2(__bfloat162float(v.x), __bfloat162float(v.y));
}

__device__ __forceinline__ void gload_lds16(const void* g, void* l)
{
    __builtin_amdgcn_global_load_lds(
        (const __attribute__((address_space(1))) void*)g,
        (__attribute__((address_space(3))) void*)l, 16, 0, 0);
}

// ---------------------------------------------------------------------------
// MFMA bf16 GEMM: C[M,N] = act(A[M,K] @ B + bias), B given TRANSPOSED as
// Bt[N][K] row-major. Tile 128x128, BK=32, 256 threads = 4 waves (2x2),
// each wave a 64x64 subtile = 4x4 fragments of 16x16, mfma_f32_16x16x32_bf16.
// LDS tiles linear [128 rows][32 bf16 = 64B] with 16B-chunk swizzle
// chunk ^= (row>>1)&3 (2-way bank conflict = free). Staged with
// global_load_lds width 16 using pre-swizzled per-lane global sources.
// Requires: M%128==0, N%128==0, K%32==0, 16B-aligned A/Bt rows.
// ---------------------------------------------------------------------------
template <int ACT>
__global__ __launch_bounds__(256) void mfma_gemm(
    const bf16* __restrict__ A, int lda,
    const bf16* __restrict__ Bt,
    const float* __restrict__ bias,
    bf16* __restrict__ C, int ldc, int K)
{
    __shared__ __align__(16) char lds[16384];
    char* As = lds;
    char* Bs = lds + 8192;

    const int t = threadIdx.x;
    const int wid = t >> 6, lane = t & 63;
    const int brow = blockIdx.x * 128;
    const int bcol = blockIdx.y * 128;
    const int wr = wid >> 1, wc = wid & 1;

    f32x4 acc[4][4] = {};

    for (int k0 = 0; k0 < K; k0 += 32) {
        // stage A and B tiles: each wave stages 2x1KB of each
#pragma unroll
        for (int j = 0; j < 2; ++j) {
            const int seg = wid * 2 + j;            // 0..7, wave-uniform
            const int row = seg * 16 + (lane >> 2); // 0..127
            const int clin = lane & 3;
            const int clog = clin ^ ((row >> 1) & 3);
            gload_lds16(A + (size_t)(brow + row) * lda + k0 + clog * 8,
                        As + seg * 1024);
            gload_lds16(Bt + (size_t)(bcol + row) * K + k0 + clog * 8,
                        Bs + seg * 1024);
        }
        __syncthreads();

        bf16x8 af[4], bf[4];
#pragma unroll
        for (int m = 0; m < 4; ++m) {
            const int row = wr * 64 + m * 16 + (lane & 15);
            const int cl = (lane >> 4) ^ ((row >> 1) & 3);
            af[m] = *(const bf16x8*)(As + row * 64 + cl * 16);
        }
#pragma unroll
        for (int n = 0; n < 4; ++n) {
            const int row = wc * 64 + n * 16 + (lane & 15);
            const int cl = (lane >> 4) ^ ((row >> 1) & 3);
            bf[n] = *(const bf16x8*)(Bs + row * 64 + cl * 16);
        }
#pragma unroll
        for (int m = 0; m < 4; ++m)
#pragma unroll
            for (int n = 0; n < 4; ++n)
                acc[m][n] = __builtin_amdgcn_mfma_f32_16x16x32_bf16(
                    af[m], bf[n], acc[m][n], 0, 0, 0);
        __syncthreads();
    }

    // epilogue: C/D layout col=lane&15, row=(lane>>4)*4+reg
#pragma unroll
    for (int m = 0; m < 4; ++m) {
#pragma unroll
        for (int n = 0; n < 4; ++n) {
            const int col = bcol + wc * 64 + n * 16 + (lane & 15);
            const float bv = bias[col];
#pragma unroll
            for (int r = 0; r < 4; ++r) {
                const int row = brow + wr * 64 + m * 16 + (lane >> 4) * 4 + r;
                float v = acc[m][n][r] + bv;
                if (ACT == 1) v = fmaxf(v, 0.f);
                C[(size_t)row * ldc + col] = __float2bfloat16(v);
            }
        }
    }
}

// ---------------------------------------------------------------------------
// Weight/input prep (fp32 -> bf16, transpose, pad)
// ---------------------------------------------------------------------------
__global__ void prep_xpad_kernel(const float* __restrict__ x, bf16* __restrict__ xb)
{
    const int n = blockIdx.x, k = threadIdx.x;  // 320 threads
    xb[(size_t)n * KPAD + k] =
        __float2bfloat16(k < IN_DIM ? x[(size_t)n * IN_DIM + k] : 0.f);
}

__global__ void prep_encw_kernel(const float* __restrict__ syn_w,
                                 const float* __restrict__ ant_w,
                                 bf16* __restrict__ wt)
{
    const int c = blockIdx.x, k = threadIdx.x;  // 256 blocks x 320 threads
    float v = 0.f;
    if (k < IN_DIM) v = (c < HID) ? syn_w[k * HID + c] : ant_w[k * HID + (c - HID)];
    wt[c * KPAD + k] = __float2bfloat16(v);
}

__global__ void prep_fusw_kernel(const float* __restrict__ fw, bf16* __restrict__ wt)
{
    const int c = blockIdx.x, k = threadIdx.x;  // 512 x 256
    wt[c * 256 + k] = __float2bfloat16(fw[k * D_FUSED + c]);
}

__global__ void prep_qkvw_kernel(const float* __restrict__ Wq,
                                 const float* __restrict__ Wk,
                                 const float* __restrict__ Wv,
                                 bf16* __restrict__ wt)
{
    const int blk = blockIdx.x;  // l*1536 + hd*384 + row ; 4608 blocks
    const int k = threadIdx.x;   // 512
    const int l = blk / 1536, rem = blk % 1536;
    const int hd = rem / 384, row = rem % 384;
    const int sel = row >> 7, r = row & 127;
    const float* src = (sel == 0) ? Wq : (sel == 1) ? Wk : Wv;
    wt[(size_t)blk * D_FUSED + k] =
        __float2bfloat16(src[((size_t)l * D_FUSED + k) * D_FUSED + hd * HID + r]);
}

__global__ void prep_skpw_kernel(const float* __restrict__ Ws, bf16* __restrict__ wt)
{
    const int blk = blockIdx.x;  // l*512 + c ; 1536 blocks
    const int k = threadIdx.x;   // 512
    const int l = blk >> 9, c = blk & 511;
    wt[(size_t)blk * D_FUSED + k] =
        __float2bfloat16(Ws[((size_t)l * D_FUSED + k) * D_FUSED + c]);
}

__global__ void prep_bias_kernel(const float* __restrict__ syn_b,
                                 const float* __restrict__ ant_b,
                                 const float* __restrict__ bq,
                                 const float* __restrict__ bk,
                                 const float* __restrict__ bv,
                                 float* __restrict__ benc,
                                 float* __restrict__ bqkv)
{
    const int i = blockIdx.x * 256 + threadIdx.x;
    if (i < 256) benc[i] = (i < HID) ? syn_b[i] : ant_b[i - HID];
    const int j = i - 256;
    if (j >= 0 && j < 4608) {
        const int l = j / 1536, rem = j % 1536;
        const int hd = rem / 384, row = rem % 384;
        const int sel = row >> 7, r = row & 127;
        const float* s = (sel == 0) ? bq : (sel == 1) ? bk : bv;
        bqkv[j] = s[l * D_FUSED + hd * HID + r];
    }
}

// ---------------------------------------------------------------------------
// CSR build
// ---------------------------------------------------------------------------
__global__ void zero_int_kernel(int* __restrict__ p, int n)
{
    int i = blockIdx.x * 256 + threadIdx.x;
    if (i < n) p[i] = 0;
}

__global__ void hist_kernel(const int* __restrict__ dst, int* __restrict__ deg, int E)
{
    int e = blockIdx.x * 256 + threadIdx.x;
    if (e < E) atomicAdd(&deg[dst[e]], 1);
}

__global__ __launch_bounds__(1024) void scan_kernel(const int* __restrict__ deg,
                                                    int* __restrict__ off, int n)
{
    __shared__ int sums[1024];
    int t = threadIdx.x;
    int per = (n + 1023) / 1024;
    int start = t * per;
    int s = 0;
    for (int i = 0; i < per && start + i < n; ++i) s += deg[start + i];
    sums[t] = s;
    __syncthreads();
    for (int ofs = 1; ofs < 1024; ofs <<= 1) {
        int vPrev = (t >= ofs) ? sums[t - ofs] : 0;
        __syncthreads();
        sums[t] += vPrev;
        __syncthreads();
    }
    int run = (t == 0) ? 0 : sums[t - 1];
    for (int i = 0; i < per && start + i < n; ++i) {
        off[start + i] = run;
        run += deg[start + i];
    }
    if (t == 1023) off[n] = run;
}

__global__ void scatter_kernel(const int* __restrict__ src, const int* __restrict__ dst,
                               const int* __restrict__ off, int* __restrict__ cursor,
                               int* __restrict__ csr_src, int E)
{
    int e = blockIdx.x * 256 + threadIdx.x;
    if (e < E) {
        int d = dst[e];
        int pos = atomicAdd(&cursor[d], 1);
        csr_src[off[d] + pos] = src[e];
    }
}

// ---------------------------------------------------------------------------
// Per-head online-softmax attention. qkv[n] = [q(128) | k(128) | v(128)],
// row stride 384. hsl = h_new column slice (stride 512) holding the skip
// projection; add attention output, relu, write back.
// ---------------------------------------------------------------------------
__global__ __launch_bounds__(64) void attn_head_kernel(
    const bf16* __restrict__ qkv, bf16* __restrict__ hsl,
    const int* __restrict__ off, const int* __restrict__ csr)
{
    const int n = blockIdx.x;
    const int lane = threadIdx.x;
    const float scale = 0.08838834764831845f;  // 1/sqrt(128)

    const float2 qv = ldbf2(qkv + (size_t)n * 384 + lane * 2);

    float m = -INFINITY, z = 0.f;
    float2 acc = make_float2(0.f, 0.f);

    const int s0 = off[n], s1 = off[n + 1];
    for (int e = s0; e < s1; ++e) {
        const bf16* kp = qkv + (size_t)csr[e] * 384;
        const float2 kv = ldbf2(kp + 128 + lane * 2);
        float part = qv.x * kv.x + qv.y * kv.y;
#pragma unroll
        for (int o = 32; o; o >>= 1) part += __shfl_xor(part, o);
        const float logit = part * scale;
        const float mn = fmaxf(m, logit);
        const float corr = __expf(m - mn);
        const float wgt = __expf(logit - mn);
        z = z * corr + wgt;
        const float2 vv = ldbf2(kp + 256 + lane * 2);
        acc.x = acc.x * corr + wgt * vv.x;
        acc.y = acc.y * corr + wgt * vv.y;
        m = mn;
    }

    const float inv = 1.f / (z + 1e-16f);
    const size_t ob = (size_t)n * D_FUSED + lane * 2;
    const float2 sk = ldbf2(hsl + ob);
    __hip_bfloat162 o2;
    o2.x = __float2bfloat16(fmaxf(acc.x * inv + sk.x, 0.f));
    o2.y = __float2bfloat16(fmaxf(acc.y * inv + sk.y, 0.f));
    *(__hip_bfloat162*)(hsl + ob) = o2;
}

// ---------------------------------------------------------------------------
__global__ __launch_bounds__(256) void pool_kernel(const bf16* __restrict__ h,
                                                   const int* __restrict__ batch,
                                                   float* __restrict__ pooled)
{
    const int g = blockIdx.x;
    int a = 0, b = N_NODES;
    while (a < b) { int mid = (a + b) >> 1; if (batch[mid] < g) a = mid + 1; else b = mid; }
    const int start = a;
    b = N_NODES;
    while (a < b) { int mid = (a + b) >> 1; if (batch[mid] < g + 1) a = mid + 1; else b = mid; }
    const int end = a;
    const float invc = 1.f / fmaxf((float)(end - start), 1.f);

    const int t = threadIdx.x;
    float2 s = make_float2(0.f, 0.f);
    for (int nidx = start; nidx < end; ++nidx) {
        const float2 hv = ldbf2(h + (size_t)nidx * D_FUSED + t * 2);
        s.x += hv.x; s.y += hv.y;
    }
    pooled[(size_t)g * D_FUSED + t * 2]     = s.x * invc;
    pooled[(size_t)g * D_FUSED + t * 2 + 1] = s.y * invc;
}

__global__ __launch_bounds__(128) void cls_kernel(const float* __restrict__ pooled,
                                                  const float* __restrict__ w1,
                                                  const float* __restrict__ b1,
                                                  const float* __restrict__ w2,
                                                  const float* __restrict__ b2,
                                                  float* __restrict__ out)
{
    const int g = blockIdx.x;
    const int j = threadIdx.x;
    const float* p = pooled + (size_t)g * D_FUSED;
    float acc = 0.f;
    for (int i = 0; i < D_FUSED; ++i) acc += p[i] * w1[i * HID + j];
    const float hid = fmaxf(acc + b1[j], 0.f);
    float val = hid * w2[j];
#pragma unroll
    for (int o = 32; o; o >>= 1) val += __shfl_xor(val, o);
    __shared__ float ws2[2];
    if ((threadIdx.x & 63) == 0) ws2[threadIdx.x >> 6] = val;
    __syncthreads();
    if (threadIdx.x == 0) {
        const float sum = ws2[0] + ws2[1] + b2[0];
        out[g] = 1.f / (1.f + __expf(-sum));
    }
}

// ---------------------------------------------------------------------------
extern "C" void kernel_launch(void* const* d_in, const int* in_sizes, int n_in,
                              void* d_out, int out_size, void* d_ws, size_t ws_size,
                              hipStream_t stream)
{
    const float* x        = (const float*)d_in[0];
    const int*   ei       = (const int*)d_in[1];
    const int*   batch    = (const int*)d_in[2];
    const float* syn_w    = (const float*)d_in[3];
    const float* syn_b    = (const float*)d_in[4];
    const float* ant_w    = (const float*)d_in[5];
    const float* ant_b    = (const float*)d_in[6];
    const float* fusion_w = (const float*)d_in[7];
    const float* fusion_b = (const float*)d_in[8];
    const float* Wq       = (const float*)d_in[9];
    const float* bq       = (const float*)d_in[10];
    const float* Wk       = (const float*)d_in[11];
    const float* bk       = (const float*)d_in[12];
    const float* Wv       = (const float*)d_in[13];
    const float* bv       = (const float*)d_in[14];
    const float* Wskip    = (const float*)d_in[15];
    const float* bskip    = (const float*)d_in[16];
    const float* cls_w1   = (const float*)d_in[17];
    const float* cls_b1   = (const float*)d_in[18];
    const float* cls_w2   = (const float*)d_in[19];
    const float* cls_b2   = (const float*)d_in[20];

    const int* src = ei;
    const int* dst = ei + N_EDGES;

    // ---- workspace layout (~101 MB) ----
    const size_t NV = (size_t)N_NODES * D_FUSED;
    bf16* hA   = (bf16*)d_ws;                       // N*512
    bf16* hB   = hA + NV;                           // N*512 (tenc alias: N*256)
    bf16* qkvh = hB + NV;                           // N*384 (xb alias: N*320)
    bf16* wenc = qkvh + (size_t)N_NODES * 384;      // 256*320
    bf16* wfus = wenc + 256 * KPAD;                 // 512*256
    bf16* wqkv = wfus + 512 * 256;                  // 12*384*512
    bf16* wskp = wqkv + (size_t)12 * 384 * 512;     // 3*512*512
    float* benc = (float*)(wskp + (size_t)3 * 512 * 512);  // 256
    float* bqkv = benc + 256;                       // 4608
    float* pooled = bqkv + 4608;                    // G*512
    int* deg    = (int*)(pooled + (size_t)N_GRAPHS * D_FUSED);
    int* cursor = deg + N_NODES;
    int* off    = cursor + N_NODES;
    int* csr    = off + N_NODES + 1;

    bf16* xb   = qkvh;  // N*320, dead before first qkv GEMM
    bf16* tenc = hB;    // N*256, dead before first skip GEMM

    // ---- CSR build ----
    zero_int_kernel<<<(2 * N_NODES + 255) / 256, 256, 0, stream>>>(deg, 2 * N_NODES);
    hist_kernel<<<(N_EDGES + 255) / 256, 256, 0, stream>>>(dst, deg, N_EDGES);
    scan_kernel<<<1, 1024, 0, stream>>>(deg, off, N_NODES);
    scatter_kernel<<<(N_EDGES + 255) / 256, 256, 0, stream>>>(src, dst, off, cursor, csr, N_EDGES);

    // ---- prep ----
    prep_xpad_kernel<<<N_NODES, KPAD, 0, stream>>>(x, xb);
    prep_encw_kernel<<<256, KPAD, 0, stream>>>(syn_w, ant_w, wenc);
    prep_fusw_kernel<<<512, 256, 0, stream>>>(fusion_w, wfus);
    prep_qkvw_kernel<<<4608, 512, 0, stream>>>(Wq, Wk, Wv, wqkv);
    prep_skpw_kernel<<<1536, 512, 0, stream>>>(Wskip, wskp);
    prep_bias_kernel<<<19, 256, 0, stream>>>(syn_b, ant_b, bq, bk, bv, benc, bqkv);

    // ---- encoder: relu(x @ [syn|ant]) then fusion ----
    mfma_gemm<1><<<dim3(N_NODES / 128, 2), 256, 0, stream>>>(
        xb, KPAD, wenc, benc, tenc, 256, KPAD);
    mfma_gemm<0><<<dim3(N_NODES / 128, 4), 256, 0, stream>>>(
        tenc, 256, wfus, fusion_b, hA, D_FUSED, 256);

    // ---- transformer layers ----
    bf16* hcur = hA;
    bf16* hnew = hB;
    for (int l = 0; l < N_LAYERS; ++l) {
        // skip projection -> hnew (full 512 cols)
        mfma_gemm<0><<<dim3(N_NODES / 128, 4), 256, 0, stream>>>(
            hcur, D_FUSED, wskp + (size_t)l * D_FUSED * D_FUSED,
            bskip + (size_t)l * D_FUSED, hnew, D_FUSED, D_FUSED);
        for (int hd = 0; hd < HEADS; ++hd) {
            const size_t wi = (size_t)(l * HEADS + hd);
            mfma_gemm<0><<<dim3(N_NODES / 128, 3), 256, 0, stream>>>(
                hcur, D_FUSED, wqkv + wi * 384 * D_FUSED,
                bqkv + wi * 384, qkvh, 384, D_FUSED);
            attn_head_kernel<<<N_NODES, 64, 0, stream>>>(qkvh, hnew + hd * HID, off, csr);
        }
        bf16* tmp = hcur; hcur = hnew; hnew = tmp;
    }

    // ---- pool + classify ----
    pool_kernel<<<N_GRAPHS, 256, 0, stream>>>(hcur, batch, pooled);
    cls_kernel<<<N_GRAPHS, 128, 0, stream>>>(pooled, cls_w1, cls_b1, cls_w2, cls_b2,
                                             (float*)d_out);
}

// Round 4
// 820.199 us; speedup vs baseline: 6.8637x; 1.1975x over previous
//
#include <hip/hip_runtime.h>
#include <hip/hip_bf16.h>
#include <math.h>

#define N_NODES 32768
#define N_EDGES 262144
#define N_GRAPHS 512
#define IN_DIM 300
#define KPAD 320
#define HID 128
#define HEADS 4
#define D_FUSED 512
#define N_LAYERS 3

typedef __hip_bfloat16 bf16;
typedef short bf16x8 __attribute__((ext_vector_type(8)));
typedef float f32x4 __attribute__((ext_vector_type(4)));

__device__ __forceinline__ float2 ldbf2(const bf16* p)
{
    const __hip_bfloat162 v = *(const __hip_bfloat162*)p;
    return make_float2(__bfloat162float(v.x), __bfloat162float(v.y));
}

__device__ __forceinline__ void gload_lds16(const void* g, void* l)
{
    __builtin_amdgcn_global_load_lds(
        (const __attribute__((address_space(1))) void*)g,
        (__attribute__((address_space(3))) void*)l, 16, 0, 0);
}

// ---------------------------------------------------------------------------
// MFMA bf16 GEMM (m97 structure): C[M,N] = act(A[M,K] @ B + bias), B given
// TRANSPOSED as Bt[N][K] row-major. Tile 128x128, BK=32, 256 thr = 4 waves,
// wave = 64x64 subtile = 4x4 frags of 16x16x32. LDS 16B-chunk swizzle
// chunk ^= (row>>1)&3. Requires M%128==0, N%128==0, K%32==0.
// ---------------------------------------------------------------------------
template <int ACT>
__global__ __launch_bounds__(256) void mfma_gemm(
    const bf16* __restrict__ A, int lda,
    const bf16* __restrict__ Bt,
    const float* __restrict__ bias,
    bf16* __restrict__ C, int ldc, int K)
{
    __shared__ __align__(16) char lds[16384];
    char* As = lds;
    char* Bs = lds + 8192;

    const int t = threadIdx.x;
    const int wid = t >> 6, lane = t & 63;
    const int brow = blockIdx.x * 128;
    const int bcol = blockIdx.y * 128;
    const int wr = wid >> 1, wc = wid & 1;

    f32x4 acc[4][4] = {};

    for (int k0 = 0; k0 < K; k0 += 32) {
#pragma unroll
        for (int j = 0; j < 2; ++j) {
            const int seg = wid * 2 + j;            // 0..7, wave-uniform
            const int row = seg * 16 + (lane >> 2); // 0..127
            const int clin = lane & 3;
            const int clog = clin ^ ((row >> 1) & 3);
            gload_lds16(A + (size_t)(brow + row) * lda + k0 + clog * 8,
                        As + seg * 1024);
            gload_lds16(Bt + (size_t)(bcol + row) * K + k0 + clog * 8,
                        Bs + seg * 1024);
        }
        __syncthreads();

        bf16x8 af[4], bfr[4];
#pragma unroll
        for (int m = 0; m < 4; ++m) {
            const int row = wr * 64 + m * 16 + (lane & 15);
            const int cl = (lane >> 4) ^ ((row >> 1) & 3);
            af[m] = *(const bf16x8*)(As + row * 64 + cl * 16);
        }
#pragma unroll
        for (int n = 0; n < 4; ++n) {
            const int row = wc * 64 + n * 16 + (lane & 15);
            const int cl = (lane >> 4) ^ ((row >> 1) & 3);
            bfr[n] = *(const bf16x8*)(Bs + row * 64 + cl * 16);
        }
#pragma unroll
        for (int m = 0; m < 4; ++m)
#pragma unroll
            for (int n = 0; n < 4; ++n)
                acc[m][n] = __builtin_amdgcn_mfma_f32_16x16x32_bf16(
                    af[m], bfr[n], acc[m][n], 0, 0, 0);
        __syncthreads();
    }

#pragma unroll
    for (int m = 0; m < 4; ++m) {
#pragma unroll
        for (int n = 0; n < 4; ++n) {
            const int col = bcol + wc * 64 + n * 16 + (lane & 15);
            const float bv = bias[col];
#pragma unroll
            for (int r = 0; r < 4; ++r) {
                const int row = brow + wr * 64 + m * 16 + (lane >> 4) * 4 + r;
                float v = acc[m][n][r] + bv;
                if (ACT == 1) v = fmaxf(v, 0.f);
                C[(size_t)row * ldc + col] = __float2bfloat16(v);
            }
        }
    }
}

// ---------------------------------------------------------------------------
// Weight/input prep
// ---------------------------------------------------------------------------
__global__ void prep_xpad_kernel(const float* __restrict__ x, bf16* __restrict__ xb)
{
    const int n = blockIdx.x, k = threadIdx.x;
    xb[(size_t)n * KPAD + k] =
        __float2bfloat16(k < IN_DIM ? x[(size_t)n * IN_DIM + k] : 0.f);
}

__global__ void prep_encw_kernel(const float* __restrict__ syn_w,
                                 const float* __restrict__ ant_w,
                                 bf16* __restrict__ wt)
{
    const int c = blockIdx.x, k = threadIdx.x;
    float v = 0.f;
    if (k < IN_DIM) v = (c < HID) ? syn_w[k * HID + c] : ant_w[k * HID + (c - HID)];
    wt[c * KPAD + k] = __float2bfloat16(v);
}

__global__ void prep_fusw_kernel(const float* __restrict__ fw, bf16* __restrict__ wt)
{
    const int c = blockIdx.x, k = threadIdx.x;
    wt[c * 256 + k] = __float2bfloat16(fw[k * D_FUSED + c]);
}

__global__ void prep_qkvw_kernel(const float* __restrict__ Wq,
                                 const float* __restrict__ Wk,
                                 const float* __restrict__ Wv,
                                 bf16* __restrict__ wt)
{
    const int blk = blockIdx.x;  // l*1536 + hd*384 + row ; 4608 blocks
    const int k = threadIdx.x;   // 512
    const int l = blk / 1536, rem = blk % 1536;
    const int hd = rem / 384, row = rem % 384;
    const int sel = row >> 7, r = row & 127;
    const float* src = (sel == 0) ? Wq : (sel == 1) ? Wk : Wv;
    wt[(size_t)blk * D_FUSED + k] =
        __float2bfloat16(src[((size_t)l * D_FUSED + k) * D_FUSED + hd * HID + r]);
}

__global__ void prep_skpw_kernel(const float* __restrict__ Ws, bf16* __restrict__ wt)
{
    const int blk = blockIdx.x;  // l*512 + c
    const int k = threadIdx.x;
    const int l = blk >> 9, c = blk & 511;
    wt[(size_t)blk * D_FUSED + k] =
        __float2bfloat16(Ws[((size_t)l * D_FUSED + k) * D_FUSED + c]);
}

__global__ void prep_bias_kernel(const float* __restrict__ syn_b,
                                 const float* __restrict__ ant_b,
                                 const float* __restrict__ bq,
                                 const float* __restrict__ bk,
                                 const float* __restrict__ bv,
                                 float* __restrict__ benc,
                                 float* __restrict__ bqkv)
{
    const int i = blockIdx.x * 256 + threadIdx.x;
    if (i < 256) benc[i] = (i < HID) ? syn_b[i] : ant_b[i - HID];
    const int j = i - 256;
    if (j >= 0 && j < 4608) {
        const int l = j / 1536, rem = j % 1536;
        const int hd = rem / 384, row = rem % 384;
        const int sel = row >> 7, r = row & 127;
        const float* s = (sel == 0) ? bq : (sel == 1) ? bk : bv;
        bqkv[j] = s[l * D_FUSED + hd * HID + r];
    }
}

// ---------------------------------------------------------------------------
// CSR build: hist + hierarchical scan (128x256 partials -> scan -> offsets)
// ---------------------------------------------------------------------------
__global__ void zero_int_kernel(int* __restrict__ p, int n)
{
    int i = blockIdx.x * 256 + threadIdx.x;
    if (i < n) p[i] = 0;
}

__global__ void hist_kernel(const int* __restrict__ dst, int* __restrict__ deg, int E)
{
    int e = blockIdx.x * 256 + threadIdx.x;
    if (e < E) atomicAdd(&deg[dst[e]], 1);
}

__global__ __launch_bounds__(256) void partial_sum_kernel(const int* __restrict__ deg,
                                                          int* __restrict__ part)
{
    int v = deg[blockIdx.x * 256 + threadIdx.x];
#pragma unroll
    for (int o = 32; o; o >>= 1) v += __shfl_xor(v, o);
    __shared__ int w4[4];
    if ((threadIdx.x & 63) == 0) w4[threadIdx.x >> 6] = v;
    __syncthreads();
    if (threadIdx.x == 0) part[blockIdx.x] = w4[0] + w4[1] + w4[2] + w4[3];
}

__global__ __launch_bounds__(128) void scan_part_kernel(int* __restrict__ part)
{
    __shared__ int s[128];
    const int t = threadIdx.x;
    s[t] = part[t];
    __syncthreads();
    for (int o = 1; o < 128; o <<= 1) {
        int v = (t >= o) ? s[t - o] : 0;
        __syncthreads();
        s[t] += v;
        __syncthreads();
    }
    part[t] = (t == 0) ? 0 : s[t - 1];  // exclusive
}

__global__ __launch_bounds__(256) void off_kernel(const int* __restrict__ deg,
                                                  const int* __restrict__ part,
                                                  int* __restrict__ off)
{
    __shared__ int s[256];
    const int b = blockIdx.x, t = threadIdx.x;
    s[t] = deg[b * 256 + t];
    __syncthreads();
    for (int o = 1; o < 256; o <<= 1) {
        int v = (t >= o) ? s[t - o] : 0;
        __syncthreads();
        s[t] += v;
        __syncthreads();
    }
    const int excl = (t == 0) ? 0 : s[t - 1];
    off[b * 256 + t] = part[b] + excl;
    if (b == 127 && t == 255) off[N_NODES] = part[127] + s[255];
}

__global__ void scatter_kernel(const int* __restrict__ src, const int* __restrict__ dst,
                               const int* __restrict__ off, int* __restrict__ cursor,
                               int* __restrict__ csr_src, int E)
{
    int e = blockIdx.x * 256 + threadIdx.x;
    if (e < E) {
        int d = dst[e];
        int pos = atomicAdd(&cursor[d], 1);
        csr_src[off[d] + pos] = src[e];
    }
}

// ---------------------------------------------------------------------------
// Online-softmax attention. Block = 64*H threads; wave w = head w of node
// blockIdx.x. qkv row layout: head h at [h*384] = q(128)|k(128)|v(128),
// row stride qstride. Output: hout[n*512 + w*128 + lane*2] (holds skip proj);
// add attention, relu, write back.
// ---------------------------------------------------------------------------
__global__ __launch_bounds__(256) void attn_kernel(
    const bf16* __restrict__ qkv, int qstride, bf16* __restrict__ hout,
    const int* __restrict__ off, const int* __restrict__ csr)
{
    const int n = blockIdx.x;
    const int hd = threadIdx.x >> 6;
    const int lane = threadIdx.x & 63;
    const float scale = 0.08838834764831845f;  // 1/sqrt(128)

    const float2 qv = ldbf2(qkv + (size_t)n * qstride + hd * 384 + lane * 2);

    float m = -INFINITY, z = 0.f;
    float2 acc = make_float2(0.f, 0.f);

    const int s0 = off[n], s1 = off[n + 1];
    for (int e = s0; e < s1; ++e) {
        const bf16* kp = qkv + (size_t)csr[e] * qstride + hd * 384;
        const float2 kv = ldbf2(kp + 128 + lane * 2);
        float part = qv.x * kv.x + qv.y * kv.y;
#pragma unroll
        for (int o = 32; o; o >>= 1) part += __shfl_xor(part, o);
        const float logit = part * scale;
        const float mn = fmaxf(m, logit);
        const float corr = __expf(m - mn);
        const float wgt = __expf(logit - mn);
        z = z * corr + wgt;
        const float2 vv = ldbf2(kp + 256 + lane * 2);
        acc.x = acc.x * corr + wgt * vv.x;
        acc.y = acc.y * corr + wgt * vv.y;
        m = mn;
    }

    const float inv = 1.f / (z + 1e-16f);
    const size_t ob = (size_t)n * D_FUSED + hd * HID + lane * 2;
    const float2 sk = ldbf2(hout + ob);
    __hip_bfloat162 o2;
    o2.x = __float2bfloat16(fmaxf(acc.x * inv + sk.x, 0.f));
    o2.y = __float2bfloat16(fmaxf(acc.y * inv + sk.y, 0.f));
    *(__hip_bfloat162*)(hout + ob) = o2;
}

// ---------------------------------------------------------------------------
__global__ __launch_bounds__(256) void pool_kernel(const bf16* __restrict__ h,
                                                   const int* __restrict__ batch,
                                                   float* __restrict__ pooled)
{
    const int g = blockIdx.x;
    int a = 0, b = N_NODES;
    while (a < b) { int mid = (a + b) >> 1; if (batch[mid] < g) a = mid + 1; else b = mid; }
    const int start = a;
    b = N_NODES;
    while (a < b) { int mid = (a + b) >> 1; if (batch[mid] < g + 1) a = mid + 1; else b = mid; }
    const int end = a;
    const float invc = 1.f / fmaxf((float)(end - start), 1.f);

    const int t = threadIdx.x;
    float2 s = make_float2(0.f, 0.f);
    for (int nidx = start; nidx < end; ++nidx) {
        const float2 hv = ldbf2(h + (size_t)nidx * D_FUSED + t * 2);
        s.x += hv.x; s.y += hv.y;
    }
    pooled[(size_t)g * D_FUSED + t * 2]     = s.x * invc;
    pooled[(size_t)g * D_FUSED + t * 2 + 1] = s.y * invc;
}

__global__ __launch_bounds__(128) void cls_kernel(const float* __restrict__ pooled,
                                                  const float* __restrict__ w1,
                                                  const float* __restrict__ b1,
                                                  const float* __restrict__ w2,
                                                  const float* __restrict__ b2,
                                                  float* __restrict__ out)
{
    const int g = blockIdx.x;
    const int j = threadIdx.x;
    const float* p = pooled + (size_t)g * D_FUSED;
    float acc = 0.f;
    for (int i = 0; i < D_FUSED; ++i) acc += p[i] * w1[i * HID + j];
    const float hid = fmaxf(acc + b1[j], 0.f);
    float val = hid * w2[j];
#pragma unroll
    for (int o = 32; o; o >>= 1) val += __shfl_xor(val, o);
    __shared__ float ws2[2];
    if ((threadIdx.x & 63) == 0) ws2[threadIdx.x >> 6] = val;
    __syncthreads();
    if (threadIdx.x == 0) {
        const float sum = ws2[0] + ws2[1] + b2[0];
        out[g] = 1.f / (1.f + __expf(-sum));
    }
}

// ---------------------------------------------------------------------------
extern "C" void kernel_launch(void* const* d_in, const int* in_sizes, int n_in,
                              void* d_out, int out_size, void* d_ws, size_t ws_size,
                              hipStream_t stream)
{
    const float* x        = (const float*)d_in[0];
    const int*   ei       = (const int*)d_in[1];
    const int*   batch    = (const int*)d_in[2];
    const float* syn_w    = (const float*)d_in[3];
    const float* syn_b    = (const float*)d_in[4];
    const float* ant_w    = (const float*)d_in[5];
    const float* ant_b    = (const float*)d_in[6];
    const float* fusion_w = (const float*)d_in[7];
    const float* fusion_b = (const float*)d_in[8];
    const float* Wq       = (const float*)d_in[9];
    const float* bq       = (const float*)d_in[10];
    const float* Wk       = (const float*)d_in[11];
    const float* bk       = (const float*)d_in[12];
    const float* Wv       = (const float*)d_in[13];
    const float* bv       = (const float*)d_in[14];
    const float* Wskip    = (const float*)d_in[15];
    const float* bskip    = (const float*)d_in[16];
    const float* cls_w1   = (const float*)d_in[17];
    const float* cls_b1   = (const float*)d_in[18];
    const float* cls_w2   = (const float*)d_in[19];
    const float* cls_b2   = (const float*)d_in[20];

    const int* src = ei;
    const int* dst = ei + N_EDGES;

    // Decide fused-QKV (N=1536 buffer, ~177 MB) vs per-head fallback (~102 MB).
    const size_t NV = (size_t)N_NODES * D_FUSED;
    const size_t fixed_elems =                       // bf16 elems after qs
        256 * KPAD + 512 * 256 + (size_t)12 * 384 * 512 + (size_t)3 * 512 * 512;
    const size_t tail_bytes =                        // f32/int tail
        4 * (256 + 4608 + (size_t)N_GRAPHS * D_FUSED) +
        4 * ((size_t)2 * N_NODES + 128 + N_NODES + 1 + N_EDGES) + 256;
    const size_t need_fused = 2 * (2 * NV + (size_t)N_NODES * 1536 + fixed_elems) + tail_bytes;
    const bool fused = ws_size >= need_fused;
    const size_t qs_cols = fused ? 1536 : 384;

    bf16* hA   = (bf16*)d_ws;                          // N*512
    bf16* hB   = hA + NV;                              // N*512
    bf16* qs   = hB + NV;                              // N*qs_cols
    bf16* wenc = qs + (size_t)N_NODES * qs_cols;       // 256*320
    bf16* wfus = wenc + 256 * KPAD;                    // 512*256
    bf16* wqkv = wfus + 512 * 256;                     // 12*384*512
    bf16* wskp = wqkv + (size_t)12 * 384 * 512;        // 3*512*512
    float* benc = (float*)(wskp + (size_t)3 * 512 * 512);
    float* bqkv = benc + 256;
    float* pooled = bqkv + 4608;
    int* deg    = (int*)(pooled + (size_t)N_GRAPHS * D_FUSED);
    int* cursor = deg + N_NODES;
    int* part   = cursor + N_NODES;                    // 128
    int* off    = part + 128;                          // N+1
    int* csr    = off + N_NODES + 1;                   // E

    bf16* xb   = qs;   // N*320 <= N*384, dead before first qkv GEMM
    bf16* tenc = hB;   // N*256, dead before first skip GEMM

    // ---- CSR build ----
    zero_int_kernel<<<(2 * N_NODES + 255) / 256, 256, 0, stream>>>(deg, 2 * N_NODES);
    hist_kernel<<<N_EDGES / 256, 256, 0, stream>>>(dst, deg, N_EDGES);
    partial_sum_kernel<<<128, 256, 0, stream>>>(deg, part);
    scan_part_kernel<<<1, 128, 0, stream>>>(part);
    off_kernel<<<128, 256, 0, stream>>>(deg, part, off);
    scatter_kernel<<<N_EDGES / 256, 256, 0, stream>>>(src, dst, off, cursor, csr, N_EDGES);

    // ---- prep ----
    prep_xpad_kernel<<<N_NODES, KPAD, 0, stream>>>(x, xb);
    prep_encw_kernel<<<256, KPAD, 0, stream>>>(syn_w, ant_w, wenc);
    prep_fusw_kernel<<<512, 256, 0, stream>>>(fusion_w, wfus);
    prep_qkvw_kernel<<<4608, 512, 0, stream>>>(Wq, Wk, Wv, wqkv);
    prep_skpw_kernel<<<1536, 512, 0, stream>>>(Wskip, wskp);
    prep_bias_kernel<<<19, 256, 0, stream>>>(syn_b, ant_b, bq, bk, bv, benc, bqkv);

    // ---- encoder ----
    mfma_gemm<1><<<dim3(N_NODES / 128, 2), 256, 0, stream>>>(
        xb, KPAD, wenc, benc, tenc, 256, KPAD);
    mfma_gemm<0><<<dim3(N_NODES / 128, 4), 256, 0, stream>>>(
        tenc, 256, wfus, fusion_b, hA, D_FUSED, 256);

    // ---- transformer layers ----
    bf16* hcur = hA;
    bf16* hnew = hB;
    for (int l = 0; l < N_LAYERS; ++l) {
        // skip projection -> hnew
        mfma_gemm<0><<<dim3(N_NODES / 128, 4), 256, 0, stream>>>(
            hcur, D_FUSED, wskp + (size_t)l * D_FUSED * D_FUSED,
            bskip + (size_t)l * D_FUSED, hnew, D_FUSED, D_FUSED);
        if (fused) {
            mfma_gemm<0><<<dim3(N_NODES / 128, 12), 256, 0, stream>>>(
                hcur, D_FUSED, wqkv + (size_t)l * 1536 * D_FUSED,
                bqkv + (size_t)l * 1536, qs, 1536, D_FUSED);
            attn_kernel<<<N_NODES, 64 * HEADS, 0, stream>>>(qs, 1536, hnew, off, csr);
        } else {
            for (int hd = 0; hd < HEADS; ++hd) {
                const size_t wi = (size_t)(l * HEADS + hd);
                mfma_gemm<0><<<dim3(N_NODES / 128, 3), 256, 0, stream>>>(
                    hcur, D_FUSED, wqkv + wi * 384 * D_FUSED,
                    bqkv + wi * 384, qs, 384, D_FUSED);
                attn_kernel<<<N_NODES, 64, 0, stream>>>(qs, 384, hnew + hd * HID, off, csr);
            }
        }
        bf16* tmp = hcur; hcur = hnew; hnew = tmp;
    }

    // ---- pool + classify ----
    pool_kernel<<<N_GRAPHS, 256, 0, stream>>>(hcur, batch, pooled);
    cls_kernel<<<N_GRAPHS, 128, 0, stream>>>(pooled, cls_w1, cls_b1, cls_w2, cls_b2,
                                             (float*)d_out);
}

// Round 5
// 700.868 us; speedup vs baseline: 8.0324x; 1.1703x over previous
//
#include <hip/hip_runtime.h>
#include <hip/hip_bf16.h>
#include <math.h>

#define N_NODES 32768
#define N_EDGES 262144
#define N_GRAPHS 512
#define IN_DIM 300
#define KPAD 320
#define HID 128
#define HEADS 4
#define D_FUSED 512
#define N_LAYERS 3

typedef __hip_bfloat16 bf16;
typedef short bf16x8 __attribute__((ext_vector_type(8)));
typedef float f32x4 __attribute__((ext_vector_type(4)));

__device__ __forceinline__ float bfs_to_f(short s)
{
    unsigned u = ((unsigned)(unsigned short)s) << 16;
    return __builtin_bit_cast(float, u);
}

__device__ __forceinline__ short f_to_bfs(float v)
{
    return (short)__builtin_bit_cast(unsigned short, __float2bfloat16(v));
}

__device__ __forceinline__ void bf8_to_f32(bf16x8 v, float* f)
{
#pragma unroll
    for (int j = 0; j < 8; ++j) f[j] = bfs_to_f(v[j]);
}

__device__ __forceinline__ void gload_lds16(const void* g, void* l)
{
    __builtin_amdgcn_global_load_lds(
        (const __attribute__((address_space(1))) void*)g,
        (__attribute__((address_space(3))) void*)l, 16, 0, 0);
}

// ---------------------------------------------------------------------------
// MFMA bf16 GEMM (m97 structure): C[M,N] = act(A[M,K] @ B + bias), B given
// TRANSPOSED as Bt[N][K] row-major. Tile 128x128, BK=32, 256 thr = 4 waves,
// wave = 64x64 subtile = 4x4 frags of 16x16x32. LDS 16B-chunk swizzle
// chunk ^= (row>>1)&3. Requires M%128==0, N%128==0, K%32==0.
// ---------------------------------------------------------------------------
template <int ACT>
__global__ __launch_bounds__(256) void mfma_gemm(
    const bf16* __restrict__ A, int lda,
    const bf16* __restrict__ Bt,
    const float* __restrict__ bias,
    bf16* __restrict__ C, int ldc, int K)
{
    __shared__ __align__(16) char lds[16384];
    char* As = lds;
    char* Bs = lds + 8192;

    const int t = threadIdx.x;
    const int wid = t >> 6, lane = t & 63;
    const int brow = blockIdx.x * 128;
    const int bcol = blockIdx.y * 128;
    const int wr = wid >> 1, wc = wid & 1;

    f32x4 acc[4][4] = {};

    for (int k0 = 0; k0 < K; k0 += 32) {
#pragma unroll
        for (int j = 0; j < 2; ++j) {
            const int seg = wid * 2 + j;
            const int row = seg * 16 + (lane >> 2);
            const int clin = lane & 3;
            const int clog = clin ^ ((row >> 1) & 3);
            gload_lds16(A + (size_t)(brow + row) * lda + k0 + clog * 8,
                        As + seg * 1024);
            gload_lds16(Bt + (size_t)(bcol + row) * K + k0 + clog * 8,
                        Bs + seg * 1024);
        }
        __syncthreads();

        bf16x8 af[4], bfr[4];
#pragma unroll
        for (int m = 0; m < 4; ++m) {
            const int row = wr * 64 + m * 16 + (lane & 15);
            const int cl = (lane >> 4) ^ ((row >> 1) & 3);
            af[m] = *(const bf16x8*)(As + row * 64 + cl * 16);
        }
#pragma unroll
        for (int n = 0; n < 4; ++n) {
            const int row = wc * 64 + n * 16 + (lane & 15);
            const int cl = (lane >> 4) ^ ((row >> 1) & 3);
            bfr[n] = *(const bf16x8*)(Bs + row * 64 + cl * 16);
        }
#pragma unroll
        for (int m = 0; m < 4; ++m)
#pragma unroll
            for (int n = 0; n < 4; ++n)
                acc[m][n] = __builtin_amdgcn_mfma_f32_16x16x32_bf16(
                    af[m], bfr[n], acc[m][n], 0, 0, 0);
        __syncthreads();
    }

#pragma unroll
    for (int m = 0; m < 4; ++m) {
#pragma unroll
        for (int n = 0; n < 4; ++n) {
            const int col = bcol + wc * 64 + n * 16 + (lane & 15);
            const float bv = bias[col];
#pragma unroll
            for (int r = 0; r < 4; ++r) {
                const int row = brow + wr * 64 + m * 16 + (lane >> 4) * 4 + r;
                float v = acc[m][n][r] + bv;
                if (ACT == 1) v = fmaxf(v, 0.f);
                C[(size_t)row * ldc + col] = __float2bfloat16(v);
            }
        }
    }
}

// ---------------------------------------------------------------------------
// Fused skip|Q|K|V GEMM per layer: A[32768,512] @ Bt[2048,512]^T + bias.
// 1-D grid, bcol-fast (16 consecutive blocks share the A-panel).
// cols 0..511 -> Cskip (ld 512); cols 512..2047 -> Cqkv (ld 1536).
// ---------------------------------------------------------------------------
__global__ __launch_bounds__(256) void mfma_gemm_qkvskip(
    const bf16* __restrict__ A,
    const bf16* __restrict__ Bt,
    const float* __restrict__ bias,
    bf16* __restrict__ Cskip,
    bf16* __restrict__ Cqkv)
{
    __shared__ __align__(16) char lds[16384];
    char* As = lds;
    char* Bs = lds + 8192;

    const int t = threadIdx.x;
    const int wid = t >> 6, lane = t & 63;
    const int gid = blockIdx.x;              // 4096
    const int brow = (gid >> 4) * 128;
    const int bcol = (gid & 15) * 128;
    const int wr = wid >> 1, wc = wid & 1;

    f32x4 acc[4][4] = {};

    for (int k0 = 0; k0 < 512; k0 += 32) {
#pragma unroll
        for (int j = 0; j < 2; ++j) {
            const int seg = wid * 2 + j;
            const int row = seg * 16 + (lane >> 2);
            const int clin = lane & 3;
            const int clog = clin ^ ((row >> 1) & 3);
            gload_lds16(A + (size_t)(brow + row) * 512 + k0 + clog * 8,
                        As + seg * 1024);
            gload_lds16(Bt + (size_t)(bcol + row) * 512 + k0 + clog * 8,
                        Bs + seg * 1024);
        }
        __syncthreads();

        bf16x8 af[4], bfr[4];
#pragma unroll
        for (int m = 0; m < 4; ++m) {
            const int row = wr * 64 + m * 16 + (lane & 15);
            const int cl = (lane >> 4) ^ ((row >> 1) & 3);
            af[m] = *(const bf16x8*)(As + row * 64 + cl * 16);
        }
#pragma unroll
        for (int n = 0; n < 4; ++n) {
            const int row = wc * 64 + n * 16 + (lane & 15);
            const int cl = (lane >> 4) ^ ((row >> 1) & 3);
            bfr[n] = *(const bf16x8*)(Bs + row * 64 + cl * 16);
        }
#pragma unroll
        for (int m = 0; m < 4; ++m)
#pragma unroll
            for (int n = 0; n < 4; ++n)
                acc[m][n] = __builtin_amdgcn_mfma_f32_16x16x32_bf16(
                    af[m], bfr[n], acc[m][n], 0, 0, 0);
        __syncthreads();
    }

    const bool toQ = (bcol >= 512);
    bf16* Cd = toQ ? Cqkv : Cskip;
    const int ldc = toQ ? 1536 : 512;
    const int csub = toQ ? 512 : 0;

#pragma unroll
    for (int m = 0; m < 4; ++m) {
#pragma unroll
        for (int n = 0; n < 4; ++n) {
            const int gcol = bcol + wc * 64 + n * 16 + (lane & 15);
            const float bv = bias[gcol];
            const int col = gcol - csub;
#pragma unroll
            for (int r = 0; r < 4; ++r) {
                const int row = brow + wr * 64 + m * 16 + (lane >> 4) * 4 + r;
                Cd[(size_t)row * ldc + col] = __float2bfloat16(acc[m][n][r] + bv);
            }
        }
    }
}

// ---------------------------------------------------------------------------
// Weight/input prep
// ---------------------------------------------------------------------------
__global__ void prep_xpad_kernel(const float* __restrict__ x, bf16* __restrict__ xb)
{
    const int n = blockIdx.x, k = threadIdx.x;
    xb[(size_t)n * KPAD + k] =
        __float2bfloat16(k < IN_DIM ? x[(size_t)n * IN_DIM + k] : 0.f);
}

__global__ void prep_encw_kernel(const float* __restrict__ syn_w,
                                 const float* __restrict__ ant_w,
                                 bf16* __restrict__ wt)
{
    const int c = blockIdx.x, k = threadIdx.x;
    float v = 0.f;
    if (k < IN_DIM) v = (c < HID) ? syn_w[k * HID + c] : ant_w[k * HID + (c - HID)];
    wt[c * KPAD + k] = __float2bfloat16(v);
}

__global__ void prep_fusw_kernel(const float* __restrict__ fw, bf16* __restrict__ wt)
{
    const int c = blockIdx.x, k = threadIdx.x;
    wt[c * 256 + k] = __float2bfloat16(fw[k * D_FUSED + c]);
}

// combined per-layer weight rows: c<512 -> Wskip col c; else c-512 = hd*384+r,
// r<128 -> Wq, r<256 -> Wk, else Wv (head hd, col r&127). 6144 blocks x 512 thr.
__global__ void prep_combw_kernel(const float* __restrict__ Wskip,
                                  const float* __restrict__ Wq,
                                  const float* __restrict__ Wk,
                                  const float* __restrict__ Wv,
                                  bf16* __restrict__ wt)
{
    const int blk = blockIdx.x;  // l*2048 + c
    const int k = threadIdx.x;   // 512
    const int l = blk >> 11, c = blk & 2047;
    float v;
    if (c < 512) {
        v = Wskip[((size_t)l * D_FUSED + k) * D_FUSED + c];
    } else {
        const int cc = c - 512, hd = cc / 384, r = cc % 384;
        const int sel = r >> 7, rr = r & 127;
        const float* s = (sel == 0) ? Wq : (sel == 1) ? Wk : Wv;
        v = s[((size_t)l * D_FUSED + k) * D_FUSED + hd * HID + rr];
    }
    wt[(size_t)blk * D_FUSED + k] = __float2bfloat16(v);
}

__global__ void prep_bias_kernel(const float* __restrict__ syn_b,
                                 const float* __restrict__ ant_b,
                                 const float* __restrict__ bskip,
                                 const float* __restrict__ bq,
                                 const float* __restrict__ bk,
                                 const float* __restrict__ bv,
                                 float* __restrict__ benc,
                                 float* __restrict__ bcomb)
{
    const int i = blockIdx.x * 256 + threadIdx.x;
    if (i < 256) benc[i] = (i < HID) ? syn_b[i] : ant_b[i - HID];
    const int j = i - 256;
    if (j >= 0 && j < 6144) {
        const int l = j >> 11, c = j & 2047;
        float v;
        if (c < 512) {
            v = bskip[l * D_FUSED + c];
        } else {
            const int cc = c - 512, hd = cc / 384, r = cc % 384;
            const int sel = r >> 7, rr = r & 127;
            const float* s = (sel == 0) ? bq : (sel == 1) ? bk : bv;
            v = s[l * D_FUSED + hd * HID + rr];
        }
        bcomb[j] = v;
    }
}

// ---------------------------------------------------------------------------
// CSR build
// ---------------------------------------------------------------------------
__global__ void zero_int_kernel(int* __restrict__ p, int n)
{
    int i = blockIdx.x * 256 + threadIdx.x;
    if (i < n) p[i] = 0;
}

__global__ void hist_kernel(const int* __restrict__ dst, int* __restrict__ deg, int E)
{
    int e = blockIdx.x * 256 + threadIdx.x;
    if (e < E) atomicAdd(&deg[dst[e]], 1);
}

__global__ __launch_bounds__(256) void partial_sum_kernel(const int* __restrict__ deg,
                                                          int* __restrict__ part)
{
    int v = deg[blockIdx.x * 256 + threadIdx.x];
#pragma unroll
    for (int o = 32; o; o >>= 1) v += __shfl_xor(v, o);
    __shared__ int w4[4];
    if ((threadIdx.x & 63) == 0) w4[threadIdx.x >> 6] = v;
    __syncthreads();
    if (threadIdx.x == 0) part[blockIdx.x] = w4[0] + w4[1] + w4[2] + w4[3];
}

__global__ __launch_bounds__(128) void scan_part_kernel(int* __restrict__ part)
{
    __shared__ int s[128];
    const int t = threadIdx.x;
    s[t] = part[t];
    __syncthreads();
    for (int o = 1; o < 128; o <<= 1) {
        int v = (t >= o) ? s[t - o] : 0;
        __syncthreads();
        s[t] += v;
        __syncthreads();
    }
    part[t] = (t == 0) ? 0 : s[t - 1];  // exclusive
}

__global__ __launch_bounds__(256) void off_kernel(const int* __restrict__ deg,
                                                  const int* __restrict__ part,
                                                  int* __restrict__ off)
{
    __shared__ int s[256];
    const int b = blockIdx.x, t = threadIdx.x;
    s[t] = deg[b * 256 + t];
    __syncthreads();
    for (int o = 1; o < 256; o <<= 1) {
        int v = (t >= o) ? s[t - o] : 0;
        __syncthreads();
        s[t] += v;
        __syncthreads();
    }
    const int excl = (t == 0) ? 0 : s[t - 1];
    off[b * 256 + t] = part[b] + excl;
    if (b == 127 && t == 255) off[N_NODES] = part[127] + s[255];
}

__global__ void scatter_kernel(const int* __restrict__ src, const int* __restrict__ dst,
                               const int* __restrict__ off, int* __restrict__ cursor,
                               int* __restrict__ csr_src, int E)
{
    int e = blockIdx.x * 256 + threadIdx.x;
    if (e < E) {
        int d = dst[e];
        int pos = atomicAdd(&cursor[d], 1);
        csr_src[off[d] + pos] = src[e];
    }
}

// ---------------------------------------------------------------------------
// 4-edge-parallel online-softmax attention.
// Block = 256 = 4 waves; wave = head hd of node blockIdx.x.
// Wave splits into 4 groups of 16 lanes; group g handles edges e0+g.
// Lane sub (0..15) holds head dims sub*8..sub*8+7 as bf16x8 (16B loads).
// Per-group independent (m,z,acc) merged at the end via shfl_xor(16/32).
// qkv row: head hd at [hd*384] = q(128)|k(128)|v(128), row stride 1536.
// hout holds skip projection; add attention, relu, write back.
// ---------------------------------------------------------------------------
__global__ __launch_bounds__(256) void attn_kernel(
    const bf16* __restrict__ qkv, bf16* __restrict__ hout,
    const int* __restrict__ off, const int* __restrict__ csr)
{
    const int n = blockIdx.x;
    const int hd = threadIdx.x >> 6;
    const int lane = threadIdx.x & 63;
    const int g = lane >> 4, sub = lane & 15;
    const float scale = 0.08838834764831845f;  // 1/sqrt(128)

    const bf16* qrow = qkv + (size_t)n * 1536 + hd * 384;
    float qf[8];
    bf8_to_f32(*(const bf16x8*)(qrow + sub * 8), qf);

    float m = -1e30f, z = 0.f;
    float acc[8] = {};

    const int s0 = off[n], s1 = off[n + 1];
    for (int e0 = s0; e0 < s1; e0 += 4) {
        const int e = e0 + g;
        const bool valid = (e < s1);
        const int srcn = valid ? csr[e] : 0;
        const bf16* kp = qkv + (size_t)srcn * 1536 + hd * 384 + 128;

        float kf[8];
        bf8_to_f32(*(const bf16x8*)(kp + sub * 8), kf);
        float d = 0.f;
#pragma unroll
        for (int j = 0; j < 8; ++j) d = fmaf(qf[j], kf[j], d);
        d += __shfl_xor(d, 1);
        d += __shfl_xor(d, 2);
        d += __shfl_xor(d, 4);
        d += __shfl_xor(d, 8);

        const float logit = d * scale;
        const float mn = valid ? fmaxf(m, logit) : m;
        const float corr = __expf(m - mn);                 // 0 on first valid
        const float w = valid ? __expf(logit - mn) : 0.f;
        z = z * corr + w;

        float vf[8];
        bf8_to_f32(*(const bf16x8*)(kp + 128 + sub * 8), vf);
#pragma unroll
        for (int j = 0; j < 8; ++j) acc[j] = acc[j] * corr + w * vf[j];
        m = mn;
    }

    // merge the 4 groups
    float mm = fmaxf(m, __shfl_xor(m, 16));
    mm = fmaxf(mm, __shfl_xor(mm, 32));
    const float f = __expf(m - mm);   // m=mm=-1e30 -> exp(0)=1, z=0 anyway
    float zz = z * f;
    zz += __shfl_xor(zz, 16);
    zz += __shfl_xor(zz, 32);
    const float inv = 1.f / (zz + 1e-16f);

    float o[8];
#pragma unroll
    for (int j = 0; j < 8; ++j) {
        float a = acc[j] * f;
        a += __shfl_xor(a, 16);
        a += __shfl_xor(a, 32);
        o[j] = a * inv;
    }

    if (g == 0) {
        const size_t ob = (size_t)n * D_FUSED + hd * HID + sub * 8;
        const bf16x8 sk = *(const bf16x8*)(hout + ob);
        bf16x8 res;
#pragma unroll
        for (int j = 0; j < 8; ++j)
            res[j] = f_to_bfs(fmaxf(o[j] + bfs_to_f(sk[j]), 0.f));
        *(bf16x8*)(hout + ob) = res;
    }
}

// ---------------------------------------------------------------------------
__global__ __launch_bounds__(256) void pool_kernel(const bf16* __restrict__ h,
                                                   const int* __restrict__ batch,
                                                   float* __restrict__ pooled)
{
    const int g = blockIdx.x;
    int a = 0, b = N_NODES;
    while (a < b) { int mid = (a + b) >> 1; if (batch[mid] < g) a = mid + 1; else b = mid; }
    const int start = a;
    b = N_NODES;
    while (a < b) { int mid = (a + b) >> 1; if (batch[mid] < g + 1) a = mid + 1; else b = mid; }
    const int end = a;
    const float invc = 1.f / fmaxf((float)(end - start), 1.f);

    const int t = threadIdx.x;
    float2 s = make_float2(0.f, 0.f);
    for (int nidx = start; nidx < end; ++nidx) {
        const bf16* p = h + (size_t)nidx * D_FUSED + t * 2;
        s.x += bfs_to_f(((const short*)p)[0]);
        s.y += bfs_to_f(((const short*)p)[1]);
    }
    pooled[(size_t)g * D_FUSED + t * 2]     = s.x * invc;
    pooled[(size_t)g * D_FUSED + t * 2 + 1] = s.y * invc;
}

__global__ __launch_bounds__(128) void cls_kernel(const float* __restrict__ pooled,
                                                  const float* __restrict__ w1,
                                                  const float* __restrict__ b1,
                                                  const float* __restrict__ w2,
                                                  const float* __restrict__ b2,
                                                  float* __restrict__ out)
{
    const int g = blockIdx.x;
    const int j = threadIdx.x;
    const float* p = pooled + (size_t)g * D_FUSED;
    float acc = 0.f;
    for (int i = 0; i < D_FUSED; ++i) acc += p[i] * w1[i * HID + j];
    const float hid = fmaxf(acc + b1[j], 0.f);
    float val = hid * w2[j];
#pragma unroll
    for (int o = 32; o; o >>= 1) val += __shfl_xor(val, o);
    __shared__ float ws2[2];
    if ((threadIdx.x & 63) == 0) ws2[threadIdx.x >> 6] = val;
    __syncthreads();
    if (threadIdx.x == 0) {
        const float sum = ws2[0] + ws2[1] + b2[0];
        out[g] = 1.f / (1.f + __expf(-sum));
    }
}

// ---------------------------------------------------------------------------
extern "C" void kernel_launch(void* const* d_in, const int* in_sizes, int n_in,
                              void* d_out, int out_size, void* d_ws, size_t ws_size,
                              hipStream_t stream)
{
    const float* x        = (const float*)d_in[0];
    const int*   ei       = (const int*)d_in[1];
    const int*   batch    = (const int*)d_in[2];
    const float* syn_w    = (const float*)d_in[3];
    const float* syn_b    = (const float*)d_in[4];
    const float* ant_w    = (const float*)d_in[5];
    const float* ant_b    = (const float*)d_in[6];
    const float* fusion_w = (const float*)d_in[7];
    const float* fusion_b = (const float*)d_in[8];
    const float* Wq       = (const float*)d_in[9];
    const float* bq       = (const float*)d_in[10];
    const float* Wk       = (const float*)d_in[11];
    const float* bk       = (const float*)d_in[12];
    const float* Wv       = (const float*)d_in[13];
    const float* bv       = (const float*)d_in[14];
    const float* Wskip    = (const float*)d_in[15];
    const float* bskip    = (const float*)d_in[16];
    const float* cls_w1   = (const float*)d_in[17];
    const float* cls_b1   = (const float*)d_in[18];
    const float* cls_w2   = (const float*)d_in[19];
    const float* cls_b2   = (const float*)d_in[20];

    const int* src = ei;
    const int* dst = ei + N_EDGES;

    // ---- workspace layout (~177 MB; round-4 fused path proved ws fits) ----
    const size_t NV = (size_t)N_NODES * D_FUSED;
    bf16* hA    = (bf16*)d_ws;                         // N*512
    bf16* hB    = hA + NV;                             // N*512
    bf16* qs    = hB + NV;                             // N*1536
    bf16* wenc  = qs + (size_t)N_NODES * 1536;         // 256*320
    bf16* wfus  = wenc + 256 * KPAD;                   // 512*256
    bf16* wcomb = wfus + 512 * 256;                    // 3*2048*512
    float* benc = (float*)(wcomb + (size_t)3 * 2048 * 512);  // 256
    float* bcomb = benc + 256;                         // 6144
    float* pooled = bcomb + 6144;                      // G*512
    int* deg    = (int*)(pooled + (size_t)N_GRAPHS * D_FUSED);
    int* cursor = deg + N_NODES;
    int* part   = cursor + N_NODES;                    // 128
    int* off    = part + 128;                          // N+1
    int* csr    = off + N_NODES + 1;                   // E

    bf16* xb   = qs;   // N*320 <= N*1536, dead before first layer GEMM
    bf16* tenc = hB;   // N*256, dead before first layer GEMM

    // ---- CSR build ----
    zero_int_kernel<<<(2 * N_NODES + 255) / 256, 256, 0, stream>>>(deg, 2 * N_NODES);
    hist_kernel<<<N_EDGES / 256, 256, 0, stream>>>(dst, deg, N_EDGES);
    partial_sum_kernel<<<128, 256, 0, stream>>>(deg, part);
    scan_part_kernel<<<1, 128, 0, stream>>>(part);
    off_kernel<<<128, 256, 0, stream>>>(deg, part, off);
    scatter_kernel<<<N_EDGES / 256, 256, 0, stream>>>(src, dst, off, cursor, csr, N_EDGES);

    // ---- prep ----
    prep_xpad_kernel<<<N_NODES, KPAD, 0, stream>>>(x, xb);
    prep_encw_kernel<<<256, KPAD, 0, stream>>>(syn_w, ant_w, wenc);
    prep_fusw_kernel<<<512, 256, 0, stream>>>(fusion_w, wfus);
    prep_combw_kernel<<<6144, 512, 0, stream>>>(Wskip, Wq, Wk, Wv, wcomb);
    prep_bias_kernel<<<25, 256, 0, stream>>>(syn_b, ant_b, bskip, bq, bk, bv, benc, bcomb);

    // ---- encoder ----
    mfma_gemm<1><<<dim3(N_NODES / 128, 2), 256, 0, stream>>>(
        xb, KPAD, wenc, benc, tenc, 256, KPAD);
    mfma_gemm<0><<<dim3(N_NODES / 128, 4), 256, 0, stream>>>(
        tenc, 256, wfus, fusion_b, hA, D_FUSED, 256);

    // ---- transformer layers ----
    bf16* hcur = hA;
    bf16* hnew = hB;
    for (int l = 0; l < N_LAYERS; ++l) {
        mfma_gemm_qkvskip<<<4096, 256, 0, stream>>>(
            hcur, wcomb + (size_t)l * 2048 * D_FUSED,
            bcomb + (size_t)l * 2048, hnew, qs);
        attn_kernel<<<N_NODES, 256, 0, stream>>>(qs, hnew, off, csr);
        bf16* tmp = hcur; hcur = hnew; hnew = tmp;
    }

    // ---- pool + classify ----
    pool_kernel<<<N_GRAPHS, 256, 0, stream>>>(hcur, batch, pooled);
    cls_kernel<<<N_GRAPHS, 128, 0, stream>>>(pooled, cls_w1, cls_b1, cls_w2, cls_b2,
                                             (float*)d_out);
}

// Round 6
// 655.462 us; speedup vs baseline: 8.5888x; 1.0693x over previous
//
#include <hip/hip_runtime.h>
#include <hip/hip_bf16.h>
#include <math.h>

#define N_NODES 32768
#define N_EDGES 262144
#define N_GRAPHS 512
#define IN_DIM 300
#define KPAD 320
#define HID 128
#define HEADS 4
#define D_FUSED 512
#define N_LAYERS 3

typedef __hip_bfloat16 bf16;
typedef short bf16x8 __attribute__((ext_vector_type(8)));
typedef float f32x4 __attribute__((ext_vector_type(4)));

__device__ __forceinline__ float bfs_to_f(short s)
{
    unsigned u = ((unsigned)(unsigned short)s) << 16;
    return __builtin_bit_cast(float, u);
}

__device__ __forceinline__ short f_to_bfs(float v)
{
    return (short)__builtin_bit_cast(unsigned short, __float2bfloat16(v));
}

__device__ __forceinline__ void bf8_to_f32(bf16x8 v, float* f)
{
#pragma unroll
    for (int j = 0; j < 8; ++j) f[j] = bfs_to_f(v[j]);
}

__device__ __forceinline__ void gload_lds16(const void* g, void* l)
{
    __builtin_amdgcn_global_load_lds(
        (const __attribute__((address_space(1))) void*)g,
        (__attribute__((address_space(3))) void*)l, 16, 0, 0);
}

// ---------------------------------------------------------------------------
// 256x256-tile MFMA GEMM, BK=64, 512 thr = 8 waves (2M x 4N), double-buffered
// LDS (128 KiB), counted vmcnt(8) prefetch, setprio around MFMA clusters,
// XOR-swizzled LDS (slot ^= row&7, 16B slots), XCD-swizzled 1-D grid.
// C[M,N] = act(A[M,K] @ B + bias), B given transposed Bt[N][K] row-major.
// Split output: col < csplit -> C0 (ldc0), else C1 (ldc1, col-csplit).
// Requires M%256==0, N%256==0, K%64==0, K>=128, 16B-aligned rows.
// ---------------------------------------------------------------------------
template <int ACT>
__global__ __launch_bounds__(512, 2) void mfma_gemm256(
    const bf16* __restrict__ A, int lda,
    const bf16* __restrict__ Bt,
    const float* __restrict__ bias,
    bf16* __restrict__ C0, int ldc0,
    bf16* __restrict__ C1, int ldc1, int csplit,
    int K, int nbx)
{
    __shared__ __align__(16) char lds[131072];  // 2 bufs x (A 32K | B 32K)

    const int t = threadIdx.x;
    const int wid = t >> 6, lane = t & 63;
    const int hi = lane >> 4, li = lane & 15;
    const int wr = wid >> 2, wc = wid & 3;

    int wg = blockIdx.x;
    if ((gridDim.x & 7) == 0) {              // bijective XCD swizzle
        const int cpx = gridDim.x >> 3;
        wg = (wg & 7) * cpx + (wg >> 3);
    }
    const int mb = wg / nbx, nb = wg % nbx;
    const int brow = mb * 256, bcol = nb * 256;
    const int NT = K >> 6;

    // staging: chunk c = j*512 + wid*64 + lane; LDS linear byte c*16;
    // logical slot at linear s is (s ^ (row&7)) -> pre-swizzle global source.
    const bf16* gA[4];
    const bf16* gB[4];
    int lbA[4], lbB[4];
#pragma unroll
    for (int j = 0; j < 4; ++j) {
        const int c = j * 512 + wid * 64 + lane;
        const int row = c >> 3;
        const int colb8 = ((c & 7) ^ (row & 7)) * 8;  // bf16 units
        gA[j] = A + (size_t)(brow + row) * lda + colb8;
        gB[j] = Bt + (size_t)(bcol + row) * K + colb8;
        lbA[j] = (j * 512 + wid * 64) * 16;
        lbB[j] = 32768 + (j * 512 + wid * 64) * 16;
    }

    f32x4 acc[8][4] = {};

    auto stage = [&](int buf, int kt) {
        const int ko = kt * 64;
#pragma unroll
        for (int j = 0; j < 4; ++j)
            gload_lds16(gA[j] + ko, lds + buf * 65536 + lbA[j]);
#pragma unroll
        for (int j = 0; j < 4; ++j)
            gload_lds16(gB[j] + ko, lds + buf * 65536 + lbB[j]);
    };

    auto compute = [&](int b) {
        const char* Ab = lds + b * 65536;
        const char* Bb = Ab + 32768;
        bf16x8 bfrag[4][2];
#pragma unroll
        for (int n = 0; n < 4; ++n)
#pragma unroll
            for (int ks = 0; ks < 2; ++ks) {
                const int row = wc * 64 + n * 16 + li;
                bfrag[n][ks] = *(const bf16x8*)(
                    Bb + row * 128 + (((ks * 4 + hi) ^ (row & 7)) << 4));
            }
#pragma unroll
        for (int p = 0; p < 4; ++p) {
            bf16x8 afrag[2][2];
#pragma unroll
            for (int mm = 0; mm < 2; ++mm)
#pragma unroll
                for (int ks = 0; ks < 2; ++ks) {
                    const int row = wr * 128 + (p * 2 + mm) * 16 + li;
                    afrag[mm][ks] = *(const bf16x8*)(
                        Ab + row * 128 + (((ks * 4 + hi) ^ (row & 7)) << 4));
                }
            __builtin_amdgcn_s_setprio(1);
#pragma unroll
            for (int mm = 0; mm < 2; ++mm)
#pragma unroll
                for (int n = 0; n < 4; ++n)
#pragma unroll
                    for (int ks = 0; ks < 2; ++ks)
                        acc[p * 2 + mm][n] = __builtin_amdgcn_mfma_f32_16x16x32_bf16(
                            afrag[mm][ks], bfrag[n][ks], acc[p * 2 + mm][n], 0, 0, 0);
            __builtin_amdgcn_s_setprio(0);
        }
    };

    stage(0, 0);
    for (int kt = 0; kt < NT - 1; ++kt) {
        const int b = kt & 1;
        stage(b ^ 1, kt + 1);                        // kt+1 stays in flight
        asm volatile("s_waitcnt vmcnt(8)" ::: "memory");  // kt's 8 landed
        __builtin_amdgcn_s_barrier();
        compute(b);
        asm volatile("" ::: "memory");
        __builtin_amdgcn_s_barrier();                // protect buf b before rewrite
    }
    asm volatile("s_waitcnt vmcnt(0)" ::: "memory");
    __builtin_amdgcn_s_barrier();
    compute((NT - 1) & 1);

    // epilogue: C/D layout col=li, row=hi*4+r
#pragma unroll
    for (int m = 0; m < 8; ++m) {
#pragma unroll
        for (int n = 0; n < 4; ++n) {
            const int col = bcol + wc * 64 + n * 16 + li;
            const float bv = bias[col];
            const bool lo = (col < csplit);
            bf16* Cd = lo ? C0 : C1;
            const int ldc = lo ? ldc0 : ldc1;
            const int cc = lo ? col : col - csplit;
#pragma unroll
            for (int r = 0; r < 4; ++r) {
                const int row = brow + wr * 128 + m * 16 + hi * 4 + r;
                float v = acc[m][n][r] + bv;
                if (ACT == 1) v = fmaxf(v, 0.f);
                Cd[(size_t)row * ldc + cc] = __float2bfloat16(v);
            }
        }
    }
}

// ---------------------------------------------------------------------------
// 128x128 MFMA GEMM (m97 structure) — kept for the small-N encoder GEMM.
// ---------------------------------------------------------------------------
template <int ACT>
__global__ __launch_bounds__(256) void mfma_gemm(
    const bf16* __restrict__ A, int lda,
    const bf16* __restrict__ Bt,
    const float* __restrict__ bias,
    bf16* __restrict__ C, int ldc, int K)
{
    __shared__ __align__(16) char lds[16384];
    char* As = lds;
    char* Bs = lds + 8192;

    const int t = threadIdx.x;
    const int wid = t >> 6, lane = t & 63;
    const int brow = blockIdx.x * 128;
    const int bcol = blockIdx.y * 128;
    const int wr = wid >> 1, wc = wid & 1;

    f32x4 acc[4][4] = {};

    for (int k0 = 0; k0 < K; k0 += 32) {
#pragma unroll
        for (int j = 0; j < 2; ++j) {
            const int seg = wid * 2 + j;
            const int row = seg * 16 + (lane >> 2);
            const int clin = lane & 3;
            const int clog = clin ^ ((row >> 1) & 3);
            gload_lds16(A + (size_t)(brow + row) * lda + k0 + clog * 8,
                        As + seg * 1024);
            gload_lds16(Bt + (size_t)(bcol + row) * K + k0 + clog * 8,
                        Bs + seg * 1024);
        }
        __syncthreads();

        bf16x8 af[4], bfr[4];
#pragma unroll
        for (int m = 0; m < 4; ++m) {
            const int row = wr * 64 + m * 16 + (lane & 15);
            const int cl = (lane >> 4) ^ ((row >> 1) & 3);
            af[m] = *(const bf16x8*)(As + row * 64 + cl * 16);
        }
#pragma unroll
        for (int n = 0; n < 4; ++n) {
            const int row = wc * 64 + n * 16 + (lane & 15);
            const int cl = (lane >> 4) ^ ((row >> 1) & 3);
            bfr[n] = *(const bf16x8*)(Bs + row * 64 + cl * 16);
        }
#pragma unroll
        for (int m = 0; m < 4; ++m)
#pragma unroll
            for (int n = 0; n < 4; ++n)
                acc[m][n] = __builtin_amdgcn_mfma_f32_16x16x32_bf16(
                    af[m], bfr[n], acc[m][n], 0, 0, 0);
        __syncthreads();
    }

#pragma unroll
    for (int m = 0; m < 4; ++m) {
#pragma unroll
        for (int n = 0; n < 4; ++n) {
            const int col = bcol + wc * 64 + n * 16 + (lane & 15);
            const float bv = bias[col];
#pragma unroll
            for (int r = 0; r < 4; ++r) {
                const int row = brow + wr * 64 + m * 16 + (lane >> 4) * 4 + r;
                float v = acc[m][n][r] + bv;
                if (ACT == 1) v = fmaxf(v, 0.f);
                C[(size_t)row * ldc + col] = __float2bfloat16(v);
            }
        }
    }
}

// ---------------------------------------------------------------------------
// Weight/input prep
// ---------------------------------------------------------------------------
__global__ void prep_xpad_kernel(const float* __restrict__ x, bf16* __restrict__ xb)
{
    const int n = blockIdx.x, k = threadIdx.x;
    xb[(size_t)n * KPAD + k] =
        __float2bfloat16(k < IN_DIM ? x[(size_t)n * IN_DIM + k] : 0.f);
}

__global__ void prep_encw_kernel(const float* __restrict__ syn_w,
                                 const float* __restrict__ ant_w,
                                 bf16* __restrict__ wt)
{
    const int c = blockIdx.x, k = threadIdx.x;
    float v = 0.f;
    if (k < IN_DIM) v = (c < HID) ? syn_w[k * HID + c] : ant_w[k * HID + (c - HID)];
    wt[c * KPAD + k] = __float2bfloat16(v);
}

__global__ void prep_fusw_kernel(const float* __restrict__ fw, bf16* __restrict__ wt)
{
    const int c = blockIdx.x, k = threadIdx.x;
    wt[c * 256 + k] = __float2bfloat16(fw[k * D_FUSED + c]);
}

// combined per-layer weight rows: c<512 -> Wskip col c; else c-512 = hd*384+r,
// r<128 -> Wq, r<256 -> Wk, else Wv (head hd, col r&127). 6144 blocks x 512 thr.
__global__ void prep_combw_kernel(const float* __restrict__ Wskip,
                                  const float* __restrict__ Wq,
                                  const float* __restrict__ Wk,
                                  const float* __restrict__ Wv,
                                  bf16* __restrict__ wt)
{
    const int blk = blockIdx.x;  // l*2048 + c
    const int k = threadIdx.x;   // 512
    const int l = blk >> 11, c = blk & 2047;
    float v;
    if (c < 512) {
        v = Wskip[((size_t)l * D_FUSED + k) * D_FUSED + c];
    } else {
        const int cc = c - 512, hd = cc / 384, r = cc % 384;
        const int sel = r >> 7, rr = r & 127;
        const float* s = (sel == 0) ? Wq : (sel == 1) ? Wk : Wv;
        v = s[((size_t)l * D_FUSED + k) * D_FUSED + hd * HID + rr];
    }
    wt[(size_t)blk * D_FUSED + k] = __float2bfloat16(v);
}

__global__ void prep_bias_kernel(const float* __restrict__ syn_b,
                                 const float* __restrict__ ant_b,
                                 const float* __restrict__ bskip,
                                 const float* __restrict__ bq,
                                 const float* __restrict__ bk,
                                 const float* __restrict__ bv,
                                 float* __restrict__ benc,
                                 float* __restrict__ bcomb)
{
    const int i = blockIdx.x * 256 + threadIdx.x;
    if (i < 256) benc[i] = (i < HID) ? syn_b[i] : ant_b[i - HID];
    const int j = i - 256;
    if (j >= 0 && j < 6144) {
        const int l = j >> 11, c = j & 2047;
        float v;
        if (c < 512) {
            v = bskip[l * D_FUSED + c];
        } else {
            const int cc = c - 512, hd = cc / 384, r = cc % 384;
            const int sel = r >> 7, rr = r & 127;
            const float* s = (sel == 0) ? bq : (sel == 1) ? bk : bv;
            v = s[l * D_FUSED + hd * HID + rr];
        }
        bcomb[j] = v;
    }
}

// ---------------------------------------------------------------------------
// CSR build
// ---------------------------------------------------------------------------
__global__ void zero_int_kernel(int* __restrict__ p, int n)
{
    int i = blockIdx.x * 256 + threadIdx.x;
    if (i < n) p[i] = 0;
}

__global__ void hist_kernel(const int* __restrict__ dst, int* __restrict__ deg, int E)
{
    int e = blockIdx.x * 256 + threadIdx.x;
    if (e < E) atomicAdd(&deg[dst[e]], 1);
}

__global__ __launch_bounds__(256) void partial_sum_kernel(const int* __restrict__ deg,
                                                          int* __restrict__ part)
{
    int v = deg[blockIdx.x * 256 + threadIdx.x];
#pragma unroll
    for (int o = 32; o; o >>= 1) v += __shfl_xor(v, o);
    __shared__ int w4[4];
    if ((threadIdx.x & 63) == 0) w4[threadIdx.x >> 6] = v;
    __syncthreads();
    if (threadIdx.x == 0) part[blockIdx.x] = w4[0] + w4[1] + w4[2] + w4[3];
}

__global__ __launch_bounds__(128) void scan_part_kernel(int* __restrict__ part)
{
    __shared__ int s[128];
    const int t = threadIdx.x;
    s[t] = part[t];
    __syncthreads();
    for (int o = 1; o < 128; o <<= 1) {
        int v = (t >= o) ? s[t - o] : 0;
        __syncthreads();
        s[t] += v;
        __syncthreads();
    }
    part[t] = (t == 0) ? 0 : s[t - 1];  // exclusive
}

__global__ __launch_bounds__(256) void off_kernel(const int* __restrict__ deg,
                                                  const int* __restrict__ part,
                                                  int* __restrict__ off)
{
    __shared__ int s[256];
    const int b = blockIdx.x, t = threadIdx.x;
    s[t] = deg[b * 256 + t];
    __syncthreads();
    for (int o = 1; o < 256; o <<= 1) {
        int v = (t >= o) ? s[t - o] : 0;
        __syncthreads();
        s[t] += v;
        __syncthreads();
    }
    const int excl = (t == 0) ? 0 : s[t - 1];
    off[b * 256 + t] = part[b] + excl;
    if (b == 127 && t == 255) off[N_NODES] = part[127] + s[255];
}

__global__ void scatter_kernel(const int* __restrict__ src, const int* __restrict__ dst,
                               const int* __restrict__ off, int* __restrict__ cursor,
                               int* __restrict__ csr_src, int E)
{
    int e = blockIdx.x * 256 + threadIdx.x;
    if (e < E) {
        int d = dst[e];
        int pos = atomicAdd(&cursor[d], 1);
        csr_src[off[d] + pos] = src[e];
    }
}

// ---------------------------------------------------------------------------
// 4-edge-parallel online-softmax attention (unchanged from round 5).
// ---------------------------------------------------------------------------
__global__ __launch_bounds__(256) void attn_kernel(
    const bf16* __restrict__ qkv, bf16* __restrict__ hout,
    const int* __restrict__ off, const int* __restrict__ csr)
{
    const int n = blockIdx.x;
    const int hd = threadIdx.x >> 6;
    const int lane = threadIdx.x & 63;
    const int g = lane >> 4, sub = lane & 15;
    const float scale = 0.08838834764831845f;  // 1/sqrt(128)

    const bf16* qrow = qkv + (size_t)n * 1536 + hd * 384;
    float qf[8];
    bf8_to_f32(*(const bf16x8*)(qrow + sub * 8), qf);

    float m = -1e30f, z = 0.f;
    float acc[8] = {};

    const int s0 = off[n], s1 = off[n + 1];
    for (int e0 = s0; e0 < s1; e0 += 4) {
        const int e = e0 + g;
        const bool valid = (e < s1);
        const int srcn = valid ? csr[e] : 0;
        const bf16* kp = qkv + (size_t)srcn * 1536 + hd * 384 + 128;

        float kf[8];
        bf8_to_f32(*(const bf16x8*)(kp + sub * 8), kf);
        float d = 0.f;
#pragma unroll
        for (int j = 0; j < 8; ++j) d = fmaf(qf[j], kf[j], d);
        d += __shfl_xor(d, 1);
        d += __shfl_xor(d, 2);
        d += __shfl_xor(d, 4);
        d += __shfl_xor(d, 8);

        const float logit = d * scale;
        const float mn = valid ? fmaxf(m, logit) : m;
        const float corr = __expf(m - mn);
        const float w = valid ? __expf(logit - mn) : 0.f;
        z = z * corr + w;

        float vf[8];
        bf8_to_f32(*(const bf16x8*)(kp + 128 + sub * 8), vf);
#pragma unroll
        for (int j = 0; j < 8; ++j) acc[j] = acc[j] * corr + w * vf[j];
        m = mn;
    }

    // merge the 4 groups
    float mm = fmaxf(m, __shfl_xor(m, 16));
    mm = fmaxf(mm, __shfl_xor(mm, 32));
    const float f = __expf(m - mm);
    float zz = z * f;
    zz += __shfl_xor(zz, 16);
    zz += __shfl_xor(zz, 32);
    const float inv = 1.f / (zz + 1e-16f);

    float o[8];
#pragma unroll
    for (int j = 0; j < 8; ++j) {
        float a = acc[j] * f;
        a += __shfl_xor(a, 16);
        a += __shfl_xor(a, 32);
        o[j] = a * inv;
    }

    if (g == 0) {
        const size_t ob = (size_t)n * D_FUSED + hd * HID + sub * 8;
        const bf16x8 sk = *(const bf16x8*)(hout + ob);
        bf16x8 res;
#pragma unroll
        for (int j = 0; j < 8; ++j)
            res[j] = f_to_bfs(fmaxf(o[j] + bfs_to_f(sk[j]), 0.f));
        *(bf16x8*)(hout + ob) = res;
    }
}

// ---------------------------------------------------------------------------
__global__ __launch_bounds__(256) void pool_kernel(const bf16* __restrict__ h,
                                                   const int* __restrict__ batch,
                                                   float* __restrict__ pooled)
{
    const int g = blockIdx.x;
    int a = 0, b = N_NODES;
    while (a < b) { int mid = (a + b) >> 1; if (batch[mid] < g) a = mid + 1; else b = mid; }
    const int start = a;
    b = N_NODES;
    while (a < b) { int mid = (a + b) >> 1; if (batch[mid] < g + 1) a = mid + 1; else b = mid; }
    const int end = a;
    const float invc = 1.f / fmaxf((float)(end - start), 1.f);

    const int t = threadIdx.x;
    float2 s = make_float2(0.f, 0.f);
    for (int nidx = start; nidx < end; ++nidx) {
        const bf16* p = h + (size_t)nidx * D_FUSED + t * 2;
        s.x += bfs_to_f(((const short*)p)[0]);
        s.y += bfs_to_f(((const short*)p)[1]);
    }
    pooled[(size_t)g * D_FUSED + t * 2]     = s.x * invc;
    pooled[(size_t)g * D_FUSED + t * 2 + 1] = s.y * invc;
}

__global__ __launch_bounds__(128) void cls_kernel(const float* __restrict__ pooled,
                                                  const float* __restrict__ w1,
                                                  const float* __restrict__ b1,
                                                  const float* __restrict__ w2,
                                                  const float* __restrict__ b2,
                                                  float* __restrict__ out)
{
    const int g = blockIdx.x;
    const int j = threadIdx.x;
    const float* p = pooled + (size_t)g * D_FUSED;
    float acc = 0.f;
    for (int i = 0; i < D_FUSED; ++i) acc += p[i] * w1[i * HID + j];
    const float hid = fmaxf(acc + b1[j], 0.f);
    float val = hid * w2[j];
#pragma unroll
    for (int o = 32; o; o >>= 1) val += __shfl_xor(val, o);
    __shared__ float ws2[2];
    if ((threadIdx.x & 63) == 0) ws2[threadIdx.x >> 6] = val;
    __syncthreads();
    if (threadIdx.x == 0) {
        const float sum = ws2[0] + ws2[1] + b2[0];
        out[g] = 1.f / (1.f + __expf(-sum));
    }
}

// ---------------------------------------------------------------------------
extern "C" void kernel_launch(void* const* d_in, const int* in_sizes, int n_in,
                              void* d_out, int out_size, void* d_ws, size_t ws_size,
                              hipStream_t stream)
{
    const float* x        = (const float*)d_in[0];
    const int*   ei       = (const int*)d_in[1];
    const int*   batch    = (const int*)d_in[2];
    const float* syn_w    = (const float*)d_in[3];
    const float* syn_b    = (const float*)d_in[4];
    const float* ant_w    = (const float*)d_in[5];
    const float* ant_b    = (const float*)d_in[6];
    const float* fusion_w = (const float*)d_in[7];
    const float* fusion_b = (const float*)d_in[8];
    const float* Wq       = (const float*)d_in[9];
    const float* bq       = (const float*)d_in[10];
    const float* Wk       = (const float*)d_in[11];
    const float* bk       = (const float*)d_in[12];
    const float* Wv       = (const float*)d_in[13];
    const float* bv       = (const float*)d_in[14];
    const float* Wskip    = (const float*)d_in[15];
    const float* bskip    = (const float*)d_in[16];
    const float* cls_w1   = (const float*)d_in[17];
    const float* cls_b1   = (const float*)d_in[18];
    const float* cls_w2   = (const float*)d_in[19];
    const float* cls_b2   = (const float*)d_in[20];

    const int* src = ei;
    const int* dst = ei + N_EDGES;

    // ---- workspace layout (~177 MB) ----
    const size_t NV = (size_t)N_NODES * D_FUSED;
    bf16* hA    = (bf16*)d_ws;                         // N*512
    bf16* hB    = hA + NV;                             // N*512
    bf16* qs    = hB + NV;                             // N*1536
    bf16* wenc  = qs + (size_t)N_NODES * 1536;         // 256*320
    bf16* wfus  = wenc + 256 * KPAD;                   // 512*256
    bf16* wcomb = wfus + 512 * 256;                    // 3*2048*512
    float* benc = (float*)(wcomb + (size_t)3 * 2048 * 512);  // 256
    float* bcomb = benc + 256;                         // 6144
    float* pooled = bcomb + 6144;                      // G*512
    int* deg    = (int*)(pooled + (size_t)N_GRAPHS * D_FUSED);
    int* cursor = deg + N_NODES;
    int* part   = cursor + N_NODES;                    // 128
    int* off    = part + 128;                          // N+1
    int* csr    = off + N_NODES + 1;                   // E

    bf16* xb   = qs;   // N*320 <= N*1536, dead before first layer GEMM
    bf16* tenc = hB;   // N*256, dead before first layer GEMM

    // ---- CSR build ----
    zero_int_kernel<<<(2 * N_NODES + 255) / 256, 256, 0, stream>>>(deg, 2 * N_NODES);
    hist_kernel<<<N_EDGES / 256, 256, 0, stream>>>(dst, deg, N_EDGES);
    partial_sum_kernel<<<128, 256, 0, stream>>>(deg, part);
    scan_part_kernel<<<1, 128, 0, stream>>>(part);
    off_kernel<<<128, 256, 0, stream>>>(deg, part, off);
    scatter_kernel<<<N_EDGES / 256, 256, 0, stream>>>(src, dst, off, cursor, csr, N_EDGES);

    // ---- prep ----
    prep_xpad_kernel<<<N_NODES, KPAD, 0, stream>>>(x, xb);
    prep_encw_kernel<<<256, KPAD, 0, stream>>>(syn_w, ant_w, wenc);
    prep_fusw_kernel<<<512, 256, 0, stream>>>(fusion_w, wfus);
    prep_combw_kernel<<<6144, 512, 0, stream>>>(Wskip, Wq, Wk, Wv, wcomb);
    prep_bias_kernel<<<25, 256, 0, stream>>>(syn_b, ant_b, bskip, bq, bk, bv, benc, bcomb);

    // ---- encoder ----
    mfma_gemm<1><<<dim3(N_NODES / 128, 2), 256, 0, stream>>>(
        xb, KPAD, wenc, benc, tenc, 256, KPAD);
    mfma_gemm256<0><<<256, 512, 0, stream>>>(
        tenc, 256, wfus, fusion_b, hA, D_FUSED, hA, D_FUSED, D_FUSED, 256, 2);

    // ---- transformer layers ----
    bf16* hcur = hA;
    bf16* hnew = hB;
    for (int l = 0; l < N_LAYERS; ++l) {
        mfma_gemm256<0><<<1024, 512, 0, stream>>>(
            hcur, D_FUSED, wcomb + (size_t)l * 2048 * D_FUSED,
            bcomb + (size_t)l * 2048,
            hnew, D_FUSED, qs, 1536, 512, D_FUSED, 8);
        attn_kernel<<<N_NODES, 256, 0, stream>>>(qs, hnew, off, csr);
        bf16* tmp = hcur; hcur = hnew; hnew = tmp;
    }

    // ---- pool + classify ----
    pool_kernel<<<N_GRAPHS, 256, 0, stream>>>(hcur, batch, pooled);
    cls_kernel<<<N_GRAPHS, 128, 0, stream>>>(pooled, cls_w1, cls_b1, cls_w2, cls_b2,
                                             (float*)d_out);
}

// Round 7
// 635.780 us; speedup vs baseline: 8.8547x; 1.0310x over previous
//
#include <hip/hip_runtime.h>
#include <hip/hip_bf16.h>
#include <math.h>

#define N_NODES 32768
#define N_EDGES 262144
#define N_GRAPHS 512
#define IN_DIM 300
#define KPAD 320
#define HID 128
#define HEADS 4
#define D_FUSED 512
#define N_LAYERS 3

typedef __hip_bfloat16 bf16;
typedef short bf16x8 __attribute__((ext_vector_type(8)));
typedef float f32x4 __attribute__((ext_vector_type(4)));

__device__ __forceinline__ float bfs_to_f(short s)
{
    unsigned u = ((unsigned)(unsigned short)s) << 16;
    return __builtin_bit_cast(float, u);
}

__device__ __forceinline__ short f_to_bfs(float v)
{
    return (short)__builtin_bit_cast(unsigned short, __float2bfloat16(v));
}

__device__ __forceinline__ void bf8_to_f32(bf16x8 v, float* f)
{
#pragma unroll
    for (int j = 0; j < 8; ++j) f[j] = bfs_to_f(v[j]);
}

__device__ __forceinline__ void gload_lds16(const void* g, void* l)
{
    __builtin_amdgcn_global_load_lds(
        (const __attribute__((address_space(1))) void*)g,
        (__attribute__((address_space(3))) void*)l, 16, 0, 0);
}

// ---------------------------------------------------------------------------
// 256x256-tile MFMA GEMM, BK=64, 512 thr = 8 waves (2M x 4N), double-buffered
// LDS (128 KiB), counted vmcnt(8) prefetch, setprio around MFMA clusters,
// XOR-swizzled LDS (slot ^= row&7, 16B slots), XCD-swizzled 1-D grid.
// K is a template param: full unroll -> compile-time LDS addressing, and
// ks-outer MFMA ordering -> dependent-accumulator distance of 8 insts.
// Split output: col < csplit -> C0 (ldc0), else C1 (ldc1, col-csplit).
// Requires M%256==0, N%256==0, K%64==0, K>=128, 16B-aligned rows.
// ---------------------------------------------------------------------------
template <int K, int ACT>
__global__ __launch_bounds__(512, 2) void mfma_gemm256(
    const bf16* __restrict__ A, int lda,
    const bf16* __restrict__ Bt,
    const float* __restrict__ bias,
    bf16* __restrict__ C0, int ldc0,
    bf16* __restrict__ C1, int ldc1, int csplit,
    int nbx)
{
    __shared__ __align__(16) char lds[131072];  // 2 bufs x (A 32K | B 32K)

    const int t = threadIdx.x;
    const int wid = t >> 6, lane = t & 63;
    const int hi = lane >> 4, li = lane & 15;
    const int wr = wid >> 2, wc = wid & 3;

    int wg = blockIdx.x;
    if ((gridDim.x & 7) == 0) {              // bijective XCD swizzle
        const int cpx = gridDim.x >> 3;
        wg = (wg & 7) * cpx + (wg >> 3);
    }
    const int mb = wg / nbx, nb = wg % nbx;
    const int brow = mb * 256, bcol = nb * 256;
    constexpr int NT = K >> 6;

    // staging: chunk c = j*512 + wid*64 + lane; LDS linear byte c*16;
    // logical slot at linear s is (s ^ (row&7)) -> pre-swizzle global source.
    const bf16* gA[4];
    const bf16* gB[4];
    int lbA[4], lbB[4];
#pragma unroll
    for (int j = 0; j < 4; ++j) {
        const int c = j * 512 + wid * 64 + lane;
        const int row = c >> 3;
        const int colb8 = ((c & 7) ^ (row & 7)) * 8;  // bf16 units
        gA[j] = A + (size_t)(brow + row) * lda + colb8;
        gB[j] = Bt + (size_t)(bcol + row) * K + colb8;
        lbA[j] = (j * 512 + wid * 64) * 16;
        lbB[j] = 32768 + (j * 512 + wid * 64) * 16;
    }

    f32x4 acc[8][4] = {};

    auto stage = [&](int buf, int kt) {
        const int ko = kt * 64;
#pragma unroll
        for (int j = 0; j < 4; ++j)
            gload_lds16(gA[j] + ko, lds + buf * 65536 + lbA[j]);
#pragma unroll
        for (int j = 0; j < 4; ++j)
            gload_lds16(gB[j] + ko, lds + buf * 65536 + lbB[j]);
    };

    auto compute = [&](int b) {
        const char* Ab = lds + b * 65536;
        const char* Bb = Ab + 32768;
        bf16x8 bfrag[4][2];
#pragma unroll
        for (int n = 0; n < 4; ++n)
#pragma unroll
            for (int ks = 0; ks < 2; ++ks) {
                const int row = wc * 64 + n * 16 + li;
                bfrag[n][ks] = *(const bf16x8*)(
                    Bb + row * 128 + (((ks * 4 + hi) ^ (row & 7)) << 4));
            }
#pragma unroll
        for (int p = 0; p < 4; ++p) {
            bf16x8 afrag[2][2];
#pragma unroll
            for (int mm = 0; mm < 2; ++mm)
#pragma unroll
                for (int ks = 0; ks < 2; ++ks) {
                    const int row = wr * 128 + (p * 2 + mm) * 16 + li;
                    afrag[mm][ks] = *(const bf16x8*)(
                        Ab + row * 128 + (((ks * 4 + hi) ^ (row & 7)) << 4));
                }
            __builtin_amdgcn_s_setprio(1);
#pragma unroll
            for (int ks = 0; ks < 2; ++ks)        // ks OUTER: dep distance 8
#pragma unroll
                for (int mm = 0; mm < 2; ++mm)
#pragma unroll
                    for (int n = 0; n < 4; ++n)
                        acc[p * 2 + mm][n] = __builtin_amdgcn_mfma_f32_16x16x32_bf16(
                            afrag[mm][ks], bfrag[n][ks], acc[p * 2 + mm][n], 0, 0, 0);
            __builtin_amdgcn_s_setprio(0);
        }
    };

    stage(0, 0);
#pragma unroll
    for (int kt = 0; kt < NT - 1; ++kt) {
        const int b = kt & 1;
        stage(b ^ 1, kt + 1);                        // kt+1 stays in flight
        asm volatile("s_waitcnt vmcnt(8)" ::: "memory");  // kt's 8 landed
        __builtin_amdgcn_s_barrier();
        compute(b);
        asm volatile("" ::: "memory");
        __builtin_amdgcn_s_barrier();                // protect buf b before rewrite
    }
    asm volatile("s_waitcnt vmcnt(0)" ::: "memory");
    __builtin_amdgcn_s_barrier();
    compute((NT - 1) & 1);

    // epilogue: C/D layout col=li, row=hi*4+r
#pragma unroll
    for (int m = 0; m < 8; ++m) {
#pragma unroll
        for (int n = 0; n < 4; ++n) {
            const int col = bcol + wc * 64 + n * 16 + li;
            const float bv = bias[col];
            const bool lo = (col < csplit);
            bf16* Cd = lo ? C0 : C1;
            const int ldc = lo ? ldc0 : ldc1;
            const int cc = lo ? col : col - csplit;
#pragma unroll
            for (int r = 0; r < 4; ++r) {
                const int row = brow + wr * 128 + m * 16 + hi * 4 + r;
                float v = acc[m][n][r] + bv;
                if (ACT == 1) v = fmaxf(v, 0.f);
                Cd[(size_t)row * ldc + cc] = __float2bfloat16(v);
            }
        }
    }
}

// ---------------------------------------------------------------------------
// 128x128 MFMA GEMM (m97 structure) — kept for the small-N encoder GEMM.
// ---------------------------------------------------------------------------
template <int ACT>
__global__ __launch_bounds__(256) void mfma_gemm(
    const bf16* __restrict__ A, int lda,
    const bf16* __restrict__ Bt,
    const float* __restrict__ bias,
    bf16* __restrict__ C, int ldc, int K)
{
    __shared__ __align__(16) char lds[16384];
    char* As = lds;
    char* Bs = lds + 8192;

    const int t = threadIdx.x;
    const int wid = t >> 6, lane = t & 63;
    const int brow = blockIdx.x * 128;
    const int bcol = blockIdx.y * 128;
    const int wr = wid >> 1, wc = wid & 1;

    f32x4 acc[4][4] = {};

    for (int k0 = 0; k0 < K; k0 += 32) {
#pragma unroll
        for (int j = 0; j < 2; ++j) {
            const int seg = wid * 2 + j;
            const int row = seg * 16 + (lane >> 2);
            const int clin = lane & 3;
            const int clog = clin ^ ((row >> 1) & 3);
            gload_lds16(A + (size_t)(brow + row) * lda + k0 + clog * 8,
                        As + seg * 1024);
            gload_lds16(Bt + (size_t)(bcol + row) * K + k0 + clog * 8,
                        Bs + seg * 1024);
        }
        __syncthreads();

        bf16x8 af[4], bfr[4];
#pragma unroll
        for (int m = 0; m < 4; ++m) {
            const int row = wr * 64 + m * 16 + (lane & 15);
            const int cl = (lane >> 4) ^ ((row >> 1) & 3);
            af[m] = *(const bf16x8*)(As + row * 64 + cl * 16);
        }
#pragma unroll
        for (int n = 0; n < 4; ++n) {
            const int row = wc * 64 + n * 16 + (lane & 15);
            const int cl = (lane >> 4) ^ ((row >> 1) & 3);
            bfr[n] = *(const bf16x8*)(Bs + row * 64 + cl * 16);
        }
#pragma unroll
        for (int m = 0; m < 4; ++m)
#pragma unroll
            for (int n = 0; n < 4; ++n)
                acc[m][n] = __builtin_amdgcn_mfma_f32_16x16x32_bf16(
                    af[m], bfr[n], acc[m][n], 0, 0, 0);
        __syncthreads();
    }

#pragma unroll
    for (int m = 0; m < 4; ++m) {
#pragma unroll
        for (int n = 0; n < 4; ++n) {
            const int col = bcol + wc * 64 + n * 16 + (lane & 15);
            const float bv = bias[col];
#pragma unroll
            for (int r = 0; r < 4; ++r) {
                const int row = brow + wr * 64 + m * 16 + (lane >> 4) * 4 + r;
                float v = acc[m][n][r] + bv;
                if (ACT == 1) v = fmaxf(v, 0.f);
                C[(size_t)row * ldc + col] = __float2bfloat16(v);
            }
        }
    }
}

// ---------------------------------------------------------------------------
// Weight/input prep
// ---------------------------------------------------------------------------
__global__ void prep_xpad_kernel(const float* __restrict__ x, bf16* __restrict__ xb)
{
    const int n = blockIdx.x, k = threadIdx.x;
    xb[(size_t)n * KPAD + k] =
        __float2bfloat16(k < IN_DIM ? x[(size_t)n * IN_DIM + k] : 0.f);
}

__global__ void prep_encw_kernel(const float* __restrict__ syn_w,
                                 const float* __restrict__ ant_w,
                                 bf16* __restrict__ wt)
{
    const int c = blockIdx.x, k = threadIdx.x;
    float v = 0.f;
    if (k < IN_DIM) v = (c < HID) ? syn_w[k * HID + c] : ant_w[k * HID + (c - HID)];
    wt[c * KPAD + k] = __float2bfloat16(v);
}

__global__ void prep_fusw_kernel(const float* __restrict__ fw, bf16* __restrict__ wt)
{
    const int c = blockIdx.x, k = threadIdx.x;
    wt[c * 256 + k] = __float2bfloat16(fw[k * D_FUSED + c]);
}

// Combined per-layer weight transpose via 32x32 LDS tiles (coalesced both
// sides). Output row c of layer l: c<512 -> Wskip col c; else cc=c-512,
// hd=cc/384, r=cc%384, sel=r>>7 -> {Wq,Wk,Wv} col hd*128+(r&127).
// All boundaries are 32-aligned so each 32-wide c-block maps to one matrix
// with contiguous source cols. Grid: 3 * 64(cb) * 16(kb), block 256.
__global__ __launch_bounds__(256) void prep_combw_kernel(
    const float* __restrict__ Wskip,
    const float* __restrict__ Wq,
    const float* __restrict__ Wk,
    const float* __restrict__ Wv,
    bf16* __restrict__ wt)
{
    __shared__ float tile[32][33];
    const int blk = blockIdx.x;
    const int l = blk >> 10, rem = blk & 1023;   // 64*16 = 1024 per layer
    const int cb = rem >> 4, kb = rem & 15;
    const int c0 = cb * 32;

    const float* mat;
    int cp0;
    if (c0 < 512) {
        mat = Wskip; cp0 = c0;
    } else {
        const int cc0 = c0 - 512;
        const int hd = cc0 / 384, r0 = cc0 % 384;
        const int sel = r0 >> 7, rr0 = r0 & 127;
        mat = (sel == 0) ? Wq : (sel == 1) ? Wk : Wv;
        cp0 = hd * 128 + rr0;
    }

    const int j = threadIdx.x & 31;    // fast dim
    const int i0 = threadIdx.x >> 5;   // 0..7
#pragma unroll
    for (int s = 0; s < 4; ++s) {
        const int i = i0 + 8 * s;      // k within tile
        tile[i][j] = mat[((size_t)l * 512 + kb * 32 + i) * 512 + cp0 + j];
    }
    __syncthreads();
#pragma unroll
    for (int s = 0; s < 4; ++s) {
        const int jj = i0 + 8 * s;     // c within tile
        wt[((size_t)l * 2048 + c0 + jj) * 512 + kb * 32 + j] =
            __float2bfloat16(tile[j][jj]);
    }
}

__global__ void prep_bias_kernel(const float* __restrict__ syn_b,
                                 const float* __restrict__ ant_b,
                                 const float* __restrict__ bskip,
                                 const float* __restrict__ bq,
                                 const float* __restrict__ bk,
                                 const float* __restrict__ bv,
                                 float* __restrict__ benc,
                                 float* __restrict__ bcomb)
{
    const int i = blockIdx.x * 256 + threadIdx.x;
    if (i < 256) benc[i] = (i < HID) ? syn_b[i] : ant_b[i - HID];
    const int j = i - 256;
    if (j >= 0 && j < 6144) {
        const int l = j >> 11, c = j & 2047;
        float v;
        if (c < 512) {
            v = bskip[l * D_FUSED + c];
        } else {
            const int cc = c - 512, hd = cc / 384, r = cc % 384;
            const int sel = r >> 7, rr = r & 127;
            const float* s = (sel == 0) ? bq : (sel == 1) ? bk : bv;
            v = s[l * D_FUSED + hd * HID + rr];
        }
        bcomb[j] = v;
    }
}

// ---------------------------------------------------------------------------
// CSR build
// ---------------------------------------------------------------------------
__global__ void zero_int_kernel(int* __restrict__ p, int n)
{
    int i = blockIdx.x * 256 + threadIdx.x;
    if (i < n) p[i] = 0;
}

__global__ void hist_kernel(const int* __restrict__ dst, int* __restrict__ deg, int E)
{
    int e = blockIdx.x * 256 + threadIdx.x;
    if (e < E) atomicAdd(&deg[dst[e]], 1);
}

__global__ __launch_bounds__(256) void partial_sum_kernel(const int* __restrict__ deg,
                                                          int* __restrict__ part)
{
    int v = deg[blockIdx.x * 256 + threadIdx.x];
#pragma unroll
    for (int o = 32; o; o >>= 1) v += __shfl_xor(v, o);
    __shared__ int w4[4];
    if ((threadIdx.x & 63) == 0) w4[threadIdx.x >> 6] = v;
    __syncthreads();
    if (threadIdx.x == 0) part[blockIdx.x] = w4[0] + w4[1] + w4[2] + w4[3];
}

__global__ __launch_bounds__(128) void scan_part_kernel(int* __restrict__ part)
{
    __shared__ int s[128];
    const int t = threadIdx.x;
    s[t] = part[t];
    __syncthreads();
    for (int o = 1; o < 128; o <<= 1) {
        int v = (t >= o) ? s[t - o] : 0;
        __syncthreads();
        s[t] += v;
        __syncthreads();
    }
    part[t] = (t == 0) ? 0 : s[t - 1];  // exclusive
}

__global__ __launch_bounds__(256) void off_kernel(const int* __restrict__ deg,
                                                  const int* __restrict__ part,
                                                  int* __restrict__ off)
{
    __shared__ int s[256];
    const int b = blockIdx.x, t = threadIdx.x;
    s[t] = deg[b * 256 + t];
    __syncthreads();
    for (int o = 1; o < 256; o <<= 1) {
        int v = (t >= o) ? s[t - o] : 0;
        __syncthreads();
        s[t] += v;
        __syncthreads();
    }
    const int excl = (t == 0) ? 0 : s[t - 1];
    off[b * 256 + t] = part[b] + excl;
    if (b == 127 && t == 255) off[N_NODES] = part[127] + s[255];
}

__global__ void scatter_kernel(const int* __restrict__ src, const int* __restrict__ dst,
                               const int* __restrict__ off, int* __restrict__ cursor,
                               int* __restrict__ csr_src, int E)
{
    int e = blockIdx.x * 256 + threadIdx.x;
    if (e < E) {
        int d = dst[e];
        int pos = atomicAdd(&cursor[d], 1);
        csr_src[off[d] + pos] = src[e];
    }
}

// ---------------------------------------------------------------------------
// 4-edge-parallel online-softmax attention (unchanged).
// ---------------------------------------------------------------------------
__global__ __launch_bounds__(256) void attn_kernel(
    const bf16* __restrict__ qkv, bf16* __restrict__ hout,
    const int* __restrict__ off, const int* __restrict__ csr)
{
    const int n = blockIdx.x;
    const int hd = threadIdx.x >> 6;
    const int lane = threadIdx.x & 63;
    const int g = lane >> 4, sub = lane & 15;
    const float scale = 0.08838834764831845f;  // 1/sqrt(128)

    const bf16* qrow = qkv + (size_t)n * 1536 + hd * 384;
    float qf[8];
    bf8_to_f32(*(const bf16x8*)(qrow + sub * 8), qf);

    float m = -1e30f, z = 0.f;
    float acc[8] = {};

    const int s0 = off[n], s1 = off[n + 1];
    for (int e0 = s0; e0 < s1; e0 += 4) {
        const int e = e0 + g;
        const bool valid = (e < s1);
        const int srcn = valid ? csr[e] : 0;
        const bf16* kp = qkv + (size_t)srcn * 1536 + hd * 384 + 128;

        float kf[8];
        bf8_to_f32(*(const bf16x8*)(kp + sub * 8), kf);
        float d = 0.f;
#pragma unroll
        for (int j = 0; j < 8; ++j) d = fmaf(qf[j], kf[j], d);
        d += __shfl_xor(d, 1);
        d += __shfl_xor(d, 2);
        d += __shfl_xor(d, 4);
        d += __shfl_xor(d, 8);

        const float logit = d * scale;
        const float mn = valid ? fmaxf(m, logit) : m;
        const float corr = __expf(m - mn);
        const float w = valid ? __expf(logit - mn) : 0.f;
        z = z * corr + w;

        float vf[8];
        bf8_to_f32(*(const bf16x8*)(kp + 128 + sub * 8), vf);
#pragma unroll
        for (int j = 0; j < 8; ++j) acc[j] = acc[j] * corr + w * vf[j];
        m = mn;
    }

    // merge the 4 groups
    float mm = fmaxf(m, __shfl_xor(m, 16));
    mm = fmaxf(mm, __shfl_xor(mm, 32));
    const float f = __expf(m - mm);
    float zz = z * f;
    zz += __shfl_xor(zz, 16);
    zz += __shfl_xor(zz, 32);
    const float inv = 1.f / (zz + 1e-16f);

    float o[8];
#pragma unroll
    for (int j = 0; j < 8; ++j) {
        float a = acc[j] * f;
        a += __shfl_xor(a, 16);
        a += __shfl_xor(a, 32);
        o[j] = a * inv;
    }

    if (g == 0) {
        const size_t ob = (size_t)n * D_FUSED + hd * HID + sub * 8;
        const bf16x8 sk = *(const bf16x8*)(hout + ob);
        bf16x8 res;
#pragma unroll
        for (int j = 0; j < 8; ++j)
            res[j] = f_to_bfs(fmaxf(o[j] + bfs_to_f(sk[j]), 0.f));
        *(bf16x8*)(hout + ob) = res;
    }
}

// ---------------------------------------------------------------------------
__global__ __launch_bounds__(256) void pool_kernel(const bf16* __restrict__ h,
                                                   const int* __restrict__ batch,
                                                   float* __restrict__ pooled)
{
    const int g = blockIdx.x;
    int a = 0, b = N_NODES;
    while (a < b) { int mid = (a + b) >> 1; if (batch[mid] < g) a = mid + 1; else b = mid; }
    const int start = a;
    b = N_NODES;
    while (a < b) { int mid = (a + b) >> 1; if (batch[mid] < g + 1) a = mid + 1; else b = mid; }
    const int end = a;
    const float invc = 1.f / fmaxf((float)(end - start), 1.f);

    const int t = threadIdx.x;
    float2 s = make_float2(0.f, 0.f);
    for (int nidx = start; nidx < end; ++nidx) {
        const bf16* p = h + (size_t)nidx * D_FUSED + t * 2;
        s.x += bfs_to_f(((const short*)p)[0]);
        s.y += bfs_to_f(((const short*)p)[1]);
    }
    pooled[(size_t)g * D_FUSED + t * 2]     = s.x * invc;
    pooled[(size_t)g * D_FUSED + t * 2 + 1] = s.y * invc;
}

__global__ __launch_bounds__(128) void cls_kernel(const float* __restrict__ pooled,
                                                  const float* __restrict__ w1,
                                                  const float* __restrict__ b1,
                                                  const float* __restrict__ w2,
                                                  const float* __restrict__ b2,
                                                  float* __restrict__ out)
{
    const int g = blockIdx.x;
    const int j = threadIdx.x;
    const float* p = pooled + (size_t)g * D_FUSED;
    float acc = 0.f;
    for (int i = 0; i < D_FUSED; ++i) acc += p[i] * w1[i * HID + j];
    const float hid = fmaxf(acc + b1[j], 0.f);
    float val = hid * w2[j];
#pragma unroll
    for (int o = 32; o; o >>= 1) val += __shfl_xor(val, o);
    __shared__ float ws2[2];
    if ((threadIdx.x & 63) == 0) ws2[threadIdx.x >> 6] = val;
    __syncthreads();
    if (threadIdx.x == 0) {
        const float sum = ws2[0] + ws2[1] + b2[0];
        out[g] = 1.f / (1.f + __expf(-sum));
    }
}

// ---------------------------------------------------------------------------
extern "C" void kernel_launch(void* const* d_in, const int* in_sizes, int n_in,
                              void* d_out, int out_size, void* d_ws, size_t ws_size,
                              hipStream_t stream)
{
    const float* x        = (const float*)d_in[0];
    const int*   ei       = (const int*)d_in[1];
    const int*   batch    = (const int*)d_in[2];
    const float* syn_w    = (const float*)d_in[3];
    const float* syn_b    = (const float*)d_in[4];
    const float* ant_w    = (const float*)d_in[5];
    const float* ant_b    = (const float*)d_in[6];
    const float* fusion_w = (const float*)d_in[7];
    const float* fusion_b = (const float*)d_in[8];
    const float* Wq       = (const float*)d_in[9];
    const float* bq       = (const float*)d_in[10];
    const float* Wk       = (const float*)d_in[11];
    const float* bk       = (const float*)d_in[12];
    const float* Wv       = (const float*)d_in[13];
    const float* bv       = (const float*)d_in[14];
    const float* Wskip    = (const float*)d_in[15];
    const float* bskip    = (const float*)d_in[16];
    const float* cls_w1   = (const float*)d_in[17];
    const float* cls_b1   = (const float*)d_in[18];
    const float* cls_w2   = (const float*)d_in[19];
    const float* cls_b2   = (const float*)d_in[20];

    const int* src = ei;
    const int* dst = ei + N_EDGES;

    // ---- workspace layout (~177 MB) ----
    const size_t NV = (size_t)N_NODES * D_FUSED;
    bf16* hA    = (bf16*)d_ws;                         // N*512
    bf16* hB    = hA + NV;                             // N*512
    bf16* qs    = hB + NV;                             // N*1536
    bf16* wenc  = qs + (size_t)N_NODES * 1536;         // 256*320
    bf16* wfus  = wenc + 256 * KPAD;                   // 512*256
    bf16* wcomb = wfus + 512 * 256;                    // 3*2048*512
    float* benc = (float*)(wcomb + (size_t)3 * 2048 * 512);  // 256
    float* bcomb = benc + 256;                         // 6144
    float* pooled = bcomb + 6144;                      // G*512
    int* deg    = (int*)(pooled + (size_t)N_GRAPHS * D_FUSED);
    int* cursor = deg + N_NODES;
    int* part   = cursor + N_NODES;                    // 128
    int* off    = part + 128;                          // N+1
    int* csr    = off + N_NODES + 1;                   // E

    bf16* xb   = qs;   // N*320 <= N*1536, dead before first layer GEMM
    bf16* tenc = hB;   // N*256, dead before first layer GEMM

    // ---- CSR build ----
    zero_int_kernel<<<(2 * N_NODES + 255) / 256, 256, 0, stream>>>(deg, 2 * N_NODES);
    hist_kernel<<<N_EDGES / 256, 256, 0, stream>>>(dst, deg, N_EDGES);
    partial_sum_kernel<<<128, 256, 0, stream>>>(deg, part);
    scan_part_kernel<<<1, 128, 0, stream>>>(part);
    off_kernel<<<128, 256, 0, stream>>>(deg, part, off);
    scatter_kernel<<<N_EDGES / 256, 256, 0, stream>>>(src, dst, off, cursor, csr, N_EDGES);

    // ---- prep ----
    prep_xpad_kernel<<<N_NODES, KPAD, 0, stream>>>(x, xb);
    prep_encw_kernel<<<256, KPAD, 0, stream>>>(syn_w, ant_w, wenc);
    prep_fusw_kernel<<<512, 256, 0, stream>>>(fusion_w, wfus);
    prep_combw_kernel<<<3072, 256, 0, stream>>>(Wskip, Wq, Wk, Wv, wcomb);
    prep_bias_kernel<<<25, 256, 0, stream>>>(syn_b, ant_b, bskip, bq, bk, bv, benc, bcomb);

    // ---- encoder ----
    mfma_gemm<1><<<dim3(N_NODES / 128, 2), 256, 0, stream>>>(
        xb, KPAD, wenc, benc, tenc, 256, KPAD);
    mfma_gemm256<256, 0><<<256, 512, 0, stream>>>(
        tenc, 256, wfus, fusion_b, hA, D_FUSED, hA, D_FUSED, D_FUSED, 2);

    // ---- transformer layers ----
    bf16* hcur = hA;
    bf16* hnew = hB;
    for (int l = 0; l < N_LAYERS; ++l) {
        mfma_gemm256<512, 0><<<1024, 512, 0, stream>>>(
            hcur, D_FUSED, wcomb + (size_t)l * 2048 * D_FUSED,
            bcomb + (size_t)l * 2048,
            hnew, D_FUSED, qs, 1536, 512, 8);
        attn_kernel<<<N_NODES, 256, 0, stream>>>(qs, hnew, off, csr);
        bf16* tmp = hcur; hcur = hnew; hnew = tmp;
    }

    // ---- pool + classify ----
    pool_kernel<<<N_GRAPHS, 256, 0, stream>>>(hcur, batch, pooled);
    cls_kernel<<<N_GRAPHS, 128, 0, stream>>>(pooled, cls_w1, cls_b1, cls_w2, cls_b2,
                                             (float*)d_out);
}